// Round 1
// baseline (374.884 us; speedup 1.0000x reference)
//
#include <hip/hip_runtime.h>
#include <cstdint>
#include <math.h>

typedef __bf16 bf16x8 __attribute__((ext_vector_type(8)));
typedef float f32x4 __attribute__((ext_vector_type(4)));
typedef unsigned short u16;

#define B_ 4
#define N_ 2048
#define D_ 1024
#define H_ 16
#define DH_ 64
#define M_ (B_*N_)   // 8192

typedef const void __attribute__((address_space(1))) gvoid;
typedef void __attribute__((address_space(3))) lvoid;

__device__ __forceinline__ void gload16(const void* g, void* l) {
  __builtin_amdgcn_global_load_lds((gvoid*)g, (lvoid*)l, 16, 0, 0);
}

__device__ __forceinline__ u16 f2bf(float f) {
  union { float f; unsigned u; } v; v.f = f;
  unsigned u = v.u;
  u += 0x7fffu + ((u >> 16) & 1u);   // RNE
  return (u16)(u >> 16);
}

// ---------------- cast fp32 -> bf16 (x4 vectorized) ----------------
__global__ __launch_bounds__(256) void cast_bf16(const float* __restrict__ src,
                                                 u16* __restrict__ dst, int n4) {
  int i = blockIdx.x * 256 + threadIdx.x;
  if (i >= n4) return;
  float4 x = ((const float4*)src)[i];
  ushort4 y;
  y.x = f2bf(x.x); y.y = f2bf(x.y); y.z = f2bf(x.z); y.w = f2bf(x.w);
  ((ushort4*)dst)[i] = y;
}

// ---------------- GEMM: out = A @ W^T  (both row-major, B^T pattern) ----
// MODE 0: write bf16 [B,H,N,Dh]   (Q/K projections)
// MODE 1: write bf16 [B,H,Dh,N]   (V projection, pre-transposed for PV)
// MODE 2: write fp32 row-major + residual (output projection)
template<int MODE>
__global__ __launch_bounds__(256) void gemm128(
    const u16* __restrict__ A,   // [8192][1024] bf16
    const u16* __restrict__ W,   // [1024][1024] bf16 (rows = out channels)
    u16* __restrict__ obf,
    const float* __restrict__ resid,
    float* __restrict__ ofp)
{
  __shared__ __align__(16) u16 As[128*32];
  __shared__ __align__(16) u16 Bs[128*32];
  const int t = threadIdx.x;
  const int lane = t & 63;
  const int w = t >> 6;
  const int wr = w >> 1, wc = w & 1;
  const int m0 = blockIdx.x * 128;
  const int n0 = blockIdx.y * 128;
  f32x4 acc[4][4] = {};

  const int r0 = t >> 2;      // staging row (+ i*64)
  const int pcb = t & 3;      // physical 8-elem col block
  const int fr = lane & 15;
  const int fg = lane >> 4;

  for (int k0 = 0; k0 < 1024; k0 += 32) {
#pragma unroll
    for (int i = 0; i < 2; ++i) {
      int r = i*64 + r0;
      int scol = k0 + ((pcb ^ (r & 3)) * 8);   // inverse-swizzled source
      gload16(A + (size_t)(m0 + r)*1024 + scol, &As[(i*256 + t)*8]);
      gload16(W + (size_t)(n0 + r)*1024 + scol, &Bs[(i*256 + t)*8]);
    }
    __syncthreads();
    bf16x8 af[4], bfr[4];
#pragma unroll
    for (int i = 0; i < 4; ++i) {
      int ra = wr*64 + i*16 + fr;
      af[i]  = *(const bf16x8*)&As[ra*32 + ((fg ^ (ra & 3)) * 8)];
      int rb = wc*64 + i*16 + fr;
      bfr[i] = *(const bf16x8*)&Bs[rb*32 + ((fg ^ (rb & 3)) * 8)];
    }
#pragma unroll
    for (int i = 0; i < 4; ++i)
#pragma unroll
      for (int j = 0; j < 4; ++j)
        acc[i][j] = __builtin_amdgcn_mfma_f32_16x16x32_bf16(af[i], bfr[j], acc[i][j], 0, 0, 0);
    __syncthreads();
  }

#pragma unroll
  for (int i = 0; i < 4; ++i) {
#pragma unroll
    for (int j = 0; j < 4; ++j) {
#pragma unroll
      for (int jj = 0; jj < 4; ++jj) {
        int row = m0 + wr*64 + i*16 + fg*4 + jj;   // verified C/D: row=(lane>>4)*4+reg
        int col = n0 + wc*64 + j*16 + fr;          //               col=lane&15
        float val = acc[i][j][jj];
        if (MODE == 0) {
          int b = row >> 11, n = row & 2047, h = col >> 6, dh = col & 63;
          obf[(((size_t)(b*H_ + h))*N_ + n)*DH_ + dh] = f2bf(val);
        } else if (MODE == 1) {
          int b = row >> 11, n = row & 2047, h = col >> 6, dh = col & 63;
          obf[(((size_t)(b*H_ + h))*DH_ + dh)*N_ + n] = f2bf(val);
        } else {
          size_t idx = (size_t)row*1024 + col;
          ofp[idx] = val + resid[idx];
        }
      }
    }
  }
}

// ---------------- flash attention ----------------
// grid (N/64, B*H); block 256 = 4 waves; wave w owns q-rows q0+w*16 .. +16
__global__ __launch_bounds__(256) void flash_attn(
    const u16* __restrict__ Qs, const u16* __restrict__ Ks,
    const u16* __restrict__ VTs, u16* __restrict__ ctx)
{
  __shared__ __align__(16) u16 Klds[64*64];
  __shared__ __align__(16) u16 Vlds[64*64];
  __shared__ __align__(16) u16 Plds[4][16*64];
  const int t = threadIdx.x;
  const int lane = t & 63;
  const int w = t >> 6;
  const int fr = lane & 15, fg = lane >> 4;
  const int q0 = blockIdx.x * 64;
  const int bh = blockIdx.y;
  const u16* Qbh = Qs  + (size_t)bh * N_ * DH_;
  const u16* Kbh = Ks  + (size_t)bh * N_ * DH_;
  const u16* Vbh = VTs + (size_t)bh * DH_ * N_;

  bf16x8 qf[2];
  {
    int qr = q0 + w*16 + fr;
    qf[0] = *(const bf16x8*)&Qbh[(size_t)qr*64 + fg*8];
    qf[1] = *(const bf16x8*)&Qbh[(size_t)qr*64 + 32 + fg*8];
  }

  float mrun[4], lrun[4];
  f32x4 o[4] = {};
#pragma unroll
  for (int j = 0; j < 4; ++j) { mrun[j] = -1e30f; lrun[j] = 0.f; }

  const int sr0 = t >> 3;    // staging row (+ i*32)
  const int spcb = t & 7;    // physical col block

  for (int kv0 = 0; kv0 < N_; kv0 += 64) {
#pragma unroll
    for (int i = 0; i < 2; ++i) {
      int r = i*32 + sr0;
      int lcb = spcb ^ (r & 7);     // inverse-swizzled source col block
      gload16(Kbh + (size_t)(kv0 + r)*64 + lcb*8, &Klds[(i*256 + t)*8]);
      gload16(Vbh + (size_t)r*N_ + kv0 + lcb*8,  &Vlds[(i*256 + t)*8]);
    }
    __syncthreads();

    // S = Q K^T (scaled later)
    f32x4 s[4] = {};
#pragma unroll
    for (int fc = 0; fc < 4; ++fc) {
      int rk = fc*16 + fr;
#pragma unroll
      for (int ks = 0; ks < 2; ++ks) {
        bf16x8 kf = *(const bf16x8*)&Klds[rk*64 + (((ks*4 + fg) ^ (rk & 7)) * 8)];
        s[fc] = __builtin_amdgcn_mfma_f32_16x16x32_bf16(qf[ks], kf, s[fc], 0, 0, 0);
      }
    }

    // online softmax: lane holds cols, 4 q-rows (fg*4+j); reduce over 16-lane groups
    float p[4][4];
#pragma unroll
    for (int j = 0; j < 4; ++j) {
      float pm = -1e30f;
#pragma unroll
      for (int fc = 0; fc < 4; ++fc) {
        float sv = s[fc][j] * 0.125f;   // 1/sqrt(64)
        p[fc][j] = sv;
        pm = fmaxf(pm, sv);
      }
      pm = fmaxf(pm, __shfl_xor(pm, 1));
      pm = fmaxf(pm, __shfl_xor(pm, 2));
      pm = fmaxf(pm, __shfl_xor(pm, 4));
      pm = fmaxf(pm, __shfl_xor(pm, 8));
      float nm = fmaxf(mrun[j], pm);
      float al = __expf(mrun[j] - nm);
      mrun[j] = nm;
      float rs = 0.f;
#pragma unroll
      for (int fc = 0; fc < 4; ++fc) {
        float e = __expf(p[fc][j] - nm);
        p[fc][j] = e;
        rs += e;
      }
      rs += __shfl_xor(rs, 1);
      rs += __shfl_xor(rs, 2);
      rs += __shfl_xor(rs, 4);
      rs += __shfl_xor(rs, 8);
      lrun[j] = lrun[j]*al + rs;
#pragma unroll
      for (int fd = 0; fd < 4; ++fd) o[fd][j] *= al;
    }

    // P -> LDS (XOR-swizzled), then re-read as A-fragments
#pragma unroll
    for (int j = 0; j < 4; ++j) {
      int row = fg*4 + j;
#pragma unroll
      for (int fc = 0; fc < 4; ++fc) {
        int lcb = fc*2 + (fr >> 3);
        Plds[w][row*64 + ((lcb ^ (row & 7))*8) + (fr & 7)] = f2bf(p[fc][j]);
      }
    }
    __syncthreads();
    bf16x8 pa[2];
#pragma unroll
    for (int ks = 0; ks < 2; ++ks)
      pa[ks] = *(const bf16x8*)&Plds[w][fr*64 + (((ks*4 + fg) ^ (fr & 7)) * 8)];

#pragma unroll
    for (int fd = 0; fd < 4; ++fd) {
      int rv = fd*16 + fr;
#pragma unroll
      for (int ks = 0; ks < 2; ++ks) {
        bf16x8 vf = *(const bf16x8*)&Vlds[rv*64 + (((ks*4 + fg) ^ (rv & 7)) * 8)];
        o[fd] = __builtin_amdgcn_mfma_f32_16x16x32_bf16(pa[ks], vf, o[fd], 0, 0, 0);
      }
    }
    __syncthreads();
  }

  // write ctx [B,N,D] bf16 (merged heads)
  int b = bh >> 4, h = bh & 15;
#pragma unroll
  for (int fd = 0; fd < 4; ++fd)
#pragma unroll
    for (int j = 0; j < 4; ++j) {
      int n = q0 + w*16 + fg*4 + j;
      int d = h*64 + fd*16 + fr;
      ctx[((size_t)b*N_ + n)*D_ + d] = f2bf(o[fd][j] / lrun[j]);
    }
}

// ---------------- LayerNorm in-place on d_out ----------------
__global__ __launch_bounds__(256) void ln_fwd(float* __restrict__ io,
    const float* __restrict__ gamma, const float* __restrict__ beta)
{
  __shared__ float red[4];
  const int t = threadIdx.x;
  const int lane = t & 63, w = t >> 6;
  float4* row = (float4*)(io + (size_t)blockIdx.x * 1024);
  float4 x = row[t];
  float s = x.x + x.y + x.z + x.w;
#pragma unroll
  for (int m = 1; m < 64; m <<= 1) s += __shfl_xor(s, m);
  if (lane == 0) red[w] = s;
  __syncthreads();
  float mean = (red[0] + red[1] + red[2] + red[3]) * (1.f/1024.f);
  __syncthreads();
  float dx0 = x.x - mean, dx1 = x.y - mean, dx2 = x.z - mean, dx3 = x.w - mean;
  float sq = dx0*dx0 + dx1*dx1 + dx2*dx2 + dx3*dx3;
#pragma unroll
  for (int m = 1; m < 64; m <<= 1) sq += __shfl_xor(sq, m);
  if (lane == 0) red[w] = sq;
  __syncthreads();
  float var = (red[0] + red[1] + red[2] + red[3]) * (1.f/1024.f);
  float rstd = rsqrtf(var + 1e-5f);
  float4 g = ((const float4*)gamma)[t];
  float4 bb = ((const float4*)beta)[t];
  float4 y;
  y.x = dx0*rstd*g.x + bb.x;
  y.y = dx1*rstd*g.y + bb.y;
  y.z = dx2*rstd*g.z + bb.z;
  y.w = dx3*rstd*g.w + bb.w;
  row[t] = y;
}

extern "C" void kernel_launch(void* const* d_in, const int* in_sizes, int n_in,
                              void* d_out, int out_size, void* d_ws, size_t ws_size,
                              hipStream_t stream) {
  const float* q     = (const float*)d_in[0];
  const float* k     = (const float*)d_in[1];
  const float* v     = (const float*)d_in[2];
  const float* Wq    = (const float*)d_in[3];
  const float* Wk    = (const float*)d_in[4];
  const float* Wv    = (const float*)d_in[5];
  const float* Wo    = (const float*)d_in[6];
  const float* gamma = (const float*)d_in[7];
  const float* beta  = (const float*)d_in[8];
  float* out = (float*)d_out;

  char* ws = (char*)d_ws;
  const size_t MB = 1024*1024;
  u16* qb  = (u16*)(ws + 0*MB);    // 16 MB each
  u16* kb  = (u16*)(ws + 16*MB);
  u16* vb  = (u16*)(ws + 32*MB);
  u16* Wqb = (u16*)(ws + 48*MB);   // 2 MB each
  u16* Wkb = (u16*)(ws + 50*MB);
  u16* Wvb = (u16*)(ws + 52*MB);
  u16* Wob = (u16*)(ws + 54*MB);
  u16* Qs  = (u16*)(ws + 56*MB);   // [B,H,N,Dh] bf16
  u16* Ks  = (u16*)(ws + 72*MB);   // [B,H,N,Dh]
  u16* VTs = (u16*)(ws + 88*MB);   // [B,H,Dh,N]
  u16* ctx = (u16*)(ws + 0*MB);    // reuse qb region after Q-proj

  const int n4big = (B_*N_*D_)/4;  // 2M float4s
  const int n4w   = (D_*D_)/4;     // 256K
  cast_bf16<<<n4big/256, 256, 0, stream>>>(q,  qb,  n4big);
  cast_bf16<<<n4big/256, 256, 0, stream>>>(k,  kb,  n4big);
  cast_bf16<<<n4big/256, 256, 0, stream>>>(v,  vb,  n4big);
  cast_bf16<<<n4w/256,   256, 0, stream>>>(Wq, Wqb, n4w);
  cast_bf16<<<n4w/256,   256, 0, stream>>>(Wk, Wkb, n4w);
  cast_bf16<<<n4w/256,   256, 0, stream>>>(Wv, Wvb, n4w);
  cast_bf16<<<n4w/256,   256, 0, stream>>>(Wo, Wob, n4w);

  dim3 gproj(M_/128, D_/128);   // (64, 8)
  gemm128<0><<<gproj, 256, 0, stream>>>(qb, Wqb, Qs,  nullptr, nullptr);
  gemm128<0><<<gproj, 256, 0, stream>>>(kb, Wkb, Ks,  nullptr, nullptr);
  gemm128<1><<<gproj, 256, 0, stream>>>(vb, Wvb, VTs, nullptr, nullptr);

  flash_attn<<<dim3(N_/64, B_*H_), 256, 0, stream>>>(Qs, Ks, VTs, ctx);

  gemm128<2><<<gproj, 256, 0, stream>>>(ctx, Wob, nullptr, q, out);

  ln_fwd<<<M_, 256, 0, stream>>>(out, gamma, beta);
}

// Round 2
// 336.572 us; speedup vs baseline: 1.1138x; 1.1138x over previous
//
#include <hip/hip_runtime.h>
#include <cstdint>
#include <math.h>

typedef __bf16 bf16x8 __attribute__((ext_vector_type(8)));
typedef float f32x4 __attribute__((ext_vector_type(4)));
typedef unsigned short u16;

#define B_ 4
#define N_ 2048
#define D_ 1024
#define H_ 16
#define DH_ 64
#define M_ (B_*N_)   // 8192

#define QSCALE (0.125f * 1.44269504088896f)   // 1/sqrt(Dh) * log2(e)

typedef const void __attribute__((address_space(1))) gvoid;
typedef void __attribute__((address_space(3))) lvoid;

__device__ __forceinline__ void gload16(const void* g, void* l) {
  __builtin_amdgcn_global_load_lds((gvoid*)g, (lvoid*)l, 16, 0, 0);
}

// hardware bf16 convert (v_cvt_pk_bf16_f32) — do NOT hand-roll RNE (m240)
__device__ __forceinline__ u16 cvt_bf(float f) {
  __bf16 h = (__bf16)f;
  return *(u16*)&h;
}

// ---------------- fused casts fp32 -> bf16 ----------------
__global__ __launch_bounds__(256) void cast_qkv(
    const float* __restrict__ a, const float* __restrict__ b, const float* __restrict__ c,
    u16* __restrict__ oa, u16* __restrict__ ob, u16* __restrict__ oc) {
  const int n4 = (B_*N_*D_)/4;
  int i = blockIdx.x * 256 + threadIdx.x;
  const float* s; u16* d;
  if (i < n4)        { s = a; d = oa; }
  else if (i < 2*n4) { s = b; d = ob; i -= n4; }
  else               { s = c; d = oc; i -= 2*n4; }
  float4 x = ((const float4*)s)[i];
  ushort4 y;
  y.x = cvt_bf(x.x); y.y = cvt_bf(x.y); y.z = cvt_bf(x.z); y.w = cvt_bf(x.w);
  ((ushort4*)d)[i] = y;
}

__global__ __launch_bounds__(256) void cast_w4(
    const float* __restrict__ a, const float* __restrict__ b,
    const float* __restrict__ c, const float* __restrict__ e,
    u16* __restrict__ oa, u16* __restrict__ ob, u16* __restrict__ oc, u16* __restrict__ oe) {
  const int n4 = (D_*D_)/4;
  int i = blockIdx.x * 256 + threadIdx.x;
  const float* s; u16* d;
  if (i < n4)        { s = a; d = oa; }
  else if (i < 2*n4) { s = b; d = ob; i -= n4; }
  else if (i < 3*n4) { s = c; d = oc; i -= 2*n4; }
  else               { s = e; d = oe; i -= 3*n4; }
  float4 x = ((const float4*)s)[i];
  ushort4 y;
  y.x = cvt_bf(x.x); y.y = cvt_bf(x.y); y.z = cvt_bf(x.z); y.w = cvt_bf(x.w);
  ((ushort4*)d)[i] = y;
}

// ---------------- GEMM: out = A @ W^T  (both row-major, B^T pattern) ----
// MODE 0: write bf16 [B,H,N,Dh] scaled by oscale   (Q/K projections)
// MODE 1: write bf16 [B,H,Dh,N]                    (V projection, pre-transposed)
// MODE 2: write fp32 row-major + residual          (output projection)
template<int MODE>
__global__ __launch_bounds__(256) void gemm128(
    const u16* __restrict__ A,   // [8192][1024] bf16
    const u16* __restrict__ W,   // [1024][1024] bf16 (rows = out channels)
    u16* __restrict__ obf,
    const float* __restrict__ resid,
    float* __restrict__ ofp,
    float oscale)
{
  __shared__ __align__(16) u16 As[128*32];
  __shared__ __align__(16) u16 Bs[128*32];
  const int t = threadIdx.x;
  const int lane = t & 63;
  const int w = t >> 6;
  const int wr = w >> 1, wc = w & 1;
  const int m0 = blockIdx.x * 128;
  const int n0 = blockIdx.y * 128;
  f32x4 acc[4][4] = {};

  const int r0 = t >> 2;      // staging row (+ i*64)
  const int pcb = t & 3;      // physical 8-elem col block
  const int fr = lane & 15;
  const int fg = lane >> 4;

  for (int k0 = 0; k0 < 1024; k0 += 32) {
#pragma unroll
    for (int i = 0; i < 2; ++i) {
      int r = i*64 + r0;
      int scol = k0 + ((pcb ^ (r & 3)) * 8);   // inverse-swizzled source
      gload16(A + (size_t)(m0 + r)*1024 + scol, &As[(i*256 + t)*8]);
      gload16(W + (size_t)(n0 + r)*1024 + scol, &Bs[(i*256 + t)*8]);
    }
    __syncthreads();
    bf16x8 af[4], bfr[4];
#pragma unroll
    for (int i = 0; i < 4; ++i) {
      int ra = wr*64 + i*16 + fr;
      af[i]  = *(const bf16x8*)&As[ra*32 + ((fg ^ (ra & 3)) * 8)];
      int rb = wc*64 + i*16 + fr;
      bfr[i] = *(const bf16x8*)&Bs[rb*32 + ((fg ^ (rb & 3)) * 8)];
    }
#pragma unroll
    for (int i = 0; i < 4; ++i)
#pragma unroll
      for (int j = 0; j < 4; ++j)
        acc[i][j] = __builtin_amdgcn_mfma_f32_16x16x32_bf16(af[i], bfr[j], acc[i][j], 0, 0, 0);
    __syncthreads();
  }

#pragma unroll
  for (int i = 0; i < 4; ++i) {
#pragma unroll
    for (int j = 0; j < 4; ++j) {
#pragma unroll
      for (int jj = 0; jj < 4; ++jj) {
        int row = m0 + wr*64 + i*16 + fg*4 + jj;   // verified C/D: row=(lane>>4)*4+reg
        int col = n0 + wc*64 + j*16 + fr;          //               col=lane&15
        float val = acc[i][j][jj];
        if (MODE == 0) {
          int b = row >> 11, n = row & 2047, h = col >> 6, dh = col & 63;
          obf[(((size_t)(b*H_ + h))*N_ + n)*DH_ + dh] = cvt_bf(val * oscale);
        } else if (MODE == 1) {
          int b = row >> 11, n = row & 2047, h = col >> 6, dh = col & 63;
          obf[(((size_t)(b*H_ + h))*DH_ + dh)*N_ + n] = cvt_bf(val);
        } else {
          size_t idx = (size_t)row*1024 + col;
          ofp[idx] = val + resid[idx];
        }
      }
    }
  }
}

// ---------------- flash attention ----------------
// grid (N/64, B*H); block 256 = 4 waves; wave w owns q-rows q0+w*16 .. +16
// Q pre-scaled by QSCALE -> scores in log2 domain, exp2 softmax.
__global__ __launch_bounds__(256) void flash_attn(
    const u16* __restrict__ Qs, const u16* __restrict__ Ks,
    const u16* __restrict__ VTs, u16* __restrict__ ctx)
{
  __shared__ __align__(16) u16 Klds[2][64*64];
  __shared__ __align__(16) u16 Vlds[2][64*64];
  __shared__ __align__(16) u16 Plds[4][16*64];
  const int t = threadIdx.x;
  const int lane = t & 63;
  const int w = t >> 6;
  const int fr = lane & 15, fg = lane >> 4;
  const int q0 = blockIdx.x * 64;
  const int bh = blockIdx.y;
  const u16* Qbh = Qs  + (size_t)bh * N_ * DH_;
  const u16* Kbh = Ks  + (size_t)bh * N_ * DH_;
  const u16* Vbh = VTs + (size_t)bh * DH_ * N_;

  bf16x8 qf[2];
  {
    int qr = q0 + w*16 + fr;
    qf[0] = *(const bf16x8*)&Qbh[(size_t)qr*64 + fg*8];
    qf[1] = *(const bf16x8*)&Qbh[(size_t)qr*64 + 32 + fg*8];
  }

  float mrun[4], lpart[4];
  f32x4 o[4] = {};
#pragma unroll
  for (int j = 0; j < 4; ++j) { mrun[j] = -1e30f; lpart[j] = 0.f; }

  const int sr0 = t >> 3;    // staging row (+ i*32)
  const int spcb = t & 7;    // physical col block

  auto stage = [&](int buf, int kv) {
#pragma unroll
    for (int i = 0; i < 2; ++i) {
      int r = i*32 + sr0;
      int lcb = spcb ^ (r & 7);     // inverse-swizzled source col block
      gload16(Kbh + (size_t)(kv + r)*64 + lcb*8, &Klds[buf][(i*256 + t)*8]);
      gload16(Vbh + (size_t)r*N_ + kv + lcb*8,  &Vlds[buf][(i*256 + t)*8]);
    }
  };

  stage(0, 0);
  __syncthreads();
  int cur = 0;

  for (int kv0 = 0; kv0 < N_; kv0 += 64) {
    if (kv0 + 64 < N_) stage(cur ^ 1, kv0 + 64);   // 2-phase prefetch (T3-min)

    // S = Q K^T  (already in log2 units: Q carries 0.125*log2e)
    f32x4 s[4] = {};
#pragma unroll
    for (int fc = 0; fc < 4; ++fc) {
      int rk = fc*16 + fr;
#pragma unroll
      for (int ks = 0; ks < 2; ++ks) {
        bf16x8 kf = *(const bf16x8*)&Klds[cur][rk*64 + (((ks*4 + fg) ^ (rk & 7)) * 8)];
        s[fc] = __builtin_amdgcn_mfma_f32_16x16x32_bf16(qf[ks], kf, s[fc], 0, 0, 0);
      }
    }

    // online softmax (exp2 domain, defer-max THR=8, deferred l-reduction)
#pragma unroll
    for (int j = 0; j < 4; ++j) {
      float pm = fmaxf(fmaxf(s[0][j], s[1][j]), fmaxf(s[2][j], s[3][j]));
      pm = fmaxf(pm, __shfl_xor(pm, 1));
      pm = fmaxf(pm, __shfl_xor(pm, 2));
      pm = fmaxf(pm, __shfl_xor(pm, 4));
      pm = fmaxf(pm, __shfl_xor(pm, 8));
      if (pm > mrun[j] + 8.f) {                    // T13 defer-max
        float al = __builtin_amdgcn_exp2f(mrun[j] - pm);
        mrun[j] = pm;
        lpart[j] *= al;
#pragma unroll
        for (int fd = 0; fd < 4; ++fd) o[fd][j] *= al;
      }
      float m = mrun[j];
      float e0 = __builtin_amdgcn_exp2f(s[0][j] - m);
      float e1 = __builtin_amdgcn_exp2f(s[1][j] - m);
      float e2 = __builtin_amdgcn_exp2f(s[2][j] - m);
      float e3 = __builtin_amdgcn_exp2f(s[3][j] - m);
      lpart[j] += (e0 + e1) + (e2 + e3);
      // P -> per-wave LDS slab (XOR-swizzled); hw bf16 cvt
      int row = fg*4 + j;
      int rs8 = (row & 7);
      int lcb0 = (0*2 + (fr >> 3)) ^ rs8;
      int lcb1 = (1*2 + (fr >> 3)) ^ rs8;
      int lcb2 = (2*2 + (fr >> 3)) ^ rs8;
      int lcb3 = (3*2 + (fr >> 3)) ^ rs8;
      int fb = fr & 7;
      Plds[w][row*64 + lcb0*8 + fb] = cvt_bf(e0);
      Plds[w][row*64 + lcb1*8 + fb] = cvt_bf(e1);
      Plds[w][row*64 + lcb2*8 + fb] = cvt_bf(e2);
      Plds[w][row*64 + lcb3*8 + fb] = cvt_bf(e3);
    }
    // no barrier: Plds[w] is wave-private (compiler orders via lgkmcnt)
    bf16x8 pa[2];
#pragma unroll
    for (int ks = 0; ks < 2; ++ks)
      pa[ks] = *(const bf16x8*)&Plds[w][fr*64 + (((ks*4 + fg) ^ (fr & 7)) * 8)];

#pragma unroll
    for (int fd = 0; fd < 4; ++fd) {
      int rv = fd*16 + fr;
#pragma unroll
      for (int ks = 0; ks < 2; ++ks) {
        bf16x8 vf = *(const bf16x8*)&Vlds[cur][rv*64 + (((ks*4 + fg) ^ (rv & 7)) * 8)];
        o[fd] = __builtin_amdgcn_mfma_f32_16x16x32_bf16(pa[ks], vf, o[fd], 0, 0, 0);
      }
    }
    __syncthreads();   // drains prefetch vmcnt + everyone done with [cur]
    cur ^= 1;
  }

  // final l reduction (deferred from the loop)
  float linv[4];
#pragma unroll
  for (int j = 0; j < 4; ++j) {
    float l = lpart[j];
    l += __shfl_xor(l, 1);
    l += __shfl_xor(l, 2);
    l += __shfl_xor(l, 4);
    l += __shfl_xor(l, 8);
    linv[j] = __builtin_amdgcn_rcpf(l);
  }

  // write ctx [B,N,D] bf16 (merged heads)
  int b = bh >> 4, h = bh & 15;
#pragma unroll
  for (int fd = 0; fd < 4; ++fd)
#pragma unroll
    for (int j = 0; j < 4; ++j) {
      int n = q0 + w*16 + fg*4 + j;
      int d = h*64 + fd*16 + fr;
      ctx[((size_t)b*N_ + n)*D_ + d] = cvt_bf(o[fd][j] * linv[j]);
    }
}

// ---------------- LayerNorm in-place on d_out ----------------
__global__ __launch_bounds__(256) void ln_fwd(float* __restrict__ io,
    const float* __restrict__ gamma, const float* __restrict__ beta)
{
  __shared__ float red[4];
  const int t = threadIdx.x;
  const int lane = t & 63, w = t >> 6;
  float4* row = (float4*)(io + (size_t)blockIdx.x * 1024);
  float4 x = row[t];
  float s = x.x + x.y + x.z + x.w;
#pragma unroll
  for (int m = 1; m < 64; m <<= 1) s += __shfl_xor(s, m);
  if (lane == 0) red[w] = s;
  __syncthreads();
  float mean = (red[0] + red[1] + red[2] + red[3]) * (1.f/1024.f);
  __syncthreads();
  float dx0 = x.x - mean, dx1 = x.y - mean, dx2 = x.z - mean, dx3 = x.w - mean;
  float sq = dx0*dx0 + dx1*dx1 + dx2*dx2 + dx3*dx3;
#pragma unroll
  for (int m = 1; m < 64; m <<= 1) sq += __shfl_xor(sq, m);
  if (lane == 0) red[w] = sq;
  __syncthreads();
  float var = (red[0] + red[1] + red[2] + red[3]) * (1.f/1024.f);
  float rstd = rsqrtf(var + 1e-5f);
  float4 g = ((const float4*)gamma)[t];
  float4 bb = ((const float4*)beta)[t];
  float4 y;
  y.x = dx0*rstd*g.x + bb.x;
  y.y = dx1*rstd*g.y + bb.y;
  y.z = dx2*rstd*g.z + bb.z;
  y.w = dx3*rstd*g.w + bb.w;
  row[t] = y;
}

extern "C" void kernel_launch(void* const* d_in, const int* in_sizes, int n_in,
                              void* d_out, int out_size, void* d_ws, size_t ws_size,
                              hipStream_t stream) {
  const float* q     = (const float*)d_in[0];
  const float* k     = (const float*)d_in[1];
  const float* v     = (const float*)d_in[2];
  const float* Wq    = (const float*)d_in[3];
  const float* Wk    = (const float*)d_in[4];
  const float* Wv    = (const float*)d_in[5];
  const float* Wo    = (const float*)d_in[6];
  const float* gamma = (const float*)d_in[7];
  const float* beta  = (const float*)d_in[8];
  float* out = (float*)d_out;

  char* ws = (char*)d_ws;
  const size_t MB = 1024*1024;
  u16* qb  = (u16*)(ws + 0*MB);    // 16 MB each
  u16* kb  = (u16*)(ws + 16*MB);
  u16* vb  = (u16*)(ws + 32*MB);
  u16* Wqb = (u16*)(ws + 48*MB);   // 2 MB each
  u16* Wkb = (u16*)(ws + 50*MB);
  u16* Wvb = (u16*)(ws + 52*MB);
  u16* Wob = (u16*)(ws + 54*MB);
  u16* Qs  = (u16*)(ws + 56*MB);   // [B,H,N,Dh] bf16 (pre-scaled by QSCALE)
  u16* Ks  = (u16*)(ws + 72*MB);   // [B,H,N,Dh]
  u16* VTs = (u16*)(ws + 88*MB);   // [B,H,Dh,N]
  u16* ctx = (u16*)(ws + 0*MB);    // reuse qb region after Q-proj

  const int n4big = (B_*N_*D_)/4;  // 2M float4s
  const int n4w   = (D_*D_)/4;     // 256K
  cast_qkv<<<3*n4big/256, 256, 0, stream>>>(q, k, v, qb, kb, vb);
  cast_w4<<<4*n4w/256, 256, 0, stream>>>(Wq, Wk, Wv, Wo, Wqb, Wkb, Wvb, Wob);

  dim3 gproj(M_/128, D_/128);   // (64, 8)
  gemm128<0><<<gproj, 256, 0, stream>>>(qb, Wqb, Qs,  nullptr, nullptr, QSCALE);
  gemm128<0><<<gproj, 256, 0, stream>>>(kb, Wkb, Ks,  nullptr, nullptr, 1.0f);
  gemm128<1><<<gproj, 256, 0, stream>>>(vb, Wvb, VTs, nullptr, nullptr, 1.0f);

  flash_attn<<<dim3(N_/64, B_*H_), 256, 0, stream>>>(Qs, Ks, VTs, ctx);

  gemm128<2><<<gproj, 256, 0, stream>>>(ctx, Wob, nullptr, q, out, 1.0f);

  ln_fwd<<<M_, 256, 0, stream>>>(out, gamma, beta);
}

// Round 3
// 244.844 us; speedup vs baseline: 1.5311x; 1.3746x over previous
//
#include <hip/hip_runtime.h>
#include <cstdint>
#include <math.h>

typedef __bf16 bf16x8 __attribute__((ext_vector_type(8)));
typedef float f32x4 __attribute__((ext_vector_type(4)));
typedef float f32x16 __attribute__((ext_vector_type(16)));
typedef int i32x2 __attribute__((ext_vector_type(2)));
typedef unsigned u32x4 __attribute__((ext_vector_type(4)));
typedef unsigned short u16;

#define B_ 4
#define N_ 2048
#define D_ 1024
#define H_ 16
#define DH_ 64
#define M_ (B_*N_)   // 8192

#define QSCALE (0.125f * 1.44269504088896f)   // 1/sqrt(Dh) * log2(e)

typedef const void __attribute__((address_space(1))) gvoid;
typedef void __attribute__((address_space(3))) lvoid;

__device__ __forceinline__ void gload16(const void* g, void* l) {
  __builtin_amdgcn_global_load_lds((gvoid*)g, (lvoid*)l, 16, 0, 0);
}

// hardware bf16 convert — do NOT hand-roll RNE (m240)
__device__ __forceinline__ u16 cvt_bf(float f) {
  __bf16 h = (__bf16)f;
  return *(u16*)&h;
}

// v_cvt_pk_bf16_f32: word = [bf16(lo) | bf16(hi)<<16]  (no builtin on gfx950)
__device__ __forceinline__ unsigned cvt_pk(float lo, float hi) {
  unsigned r;
  asm("v_cvt_pk_bf16_f32 %0, %1, %2" : "=v"(r) : "v"(lo), "v"(hi));
  return r;
}

__device__ __forceinline__ i32x2 pl32swap(unsigned a, unsigned b) {
  return __builtin_amdgcn_permlane32_swap((int)a, (int)b, false, false);
}

// ---------------- fused casts fp32 -> bf16 ----------------
__global__ __launch_bounds__(256) void cast_qkv(
    const float* __restrict__ a, const float* __restrict__ b, const float* __restrict__ c,
    u16* __restrict__ oa, u16* __restrict__ ob, u16* __restrict__ oc) {
  const int n4 = (B_*N_*D_)/4;
  int i = blockIdx.x * 256 + threadIdx.x;
  const float* s; u16* d;
  if (i < n4)        { s = a; d = oa; }
  else if (i < 2*n4) { s = b; d = ob; i -= n4; }
  else               { s = c; d = oc; i -= 2*n4; }
  float4 x = ((const float4*)s)[i];
  ushort4 y;
  y.x = cvt_bf(x.x); y.y = cvt_bf(x.y); y.z = cvt_bf(x.z); y.w = cvt_bf(x.w);
  ((ushort4*)d)[i] = y;
}

__global__ __launch_bounds__(256) void cast_w4(
    const float* __restrict__ a, const float* __restrict__ b,
    const float* __restrict__ c, const float* __restrict__ e,
    u16* __restrict__ oa, u16* __restrict__ ob, u16* __restrict__ oc, u16* __restrict__ oe) {
  const int n4 = (D_*D_)/4;
  int i = blockIdx.x * 256 + threadIdx.x;
  const float* s; u16* d;
  if (i < n4)        { s = a; d = oa; }
  else if (i < 2*n4) { s = b; d = ob; i -= n4; }
  else if (i < 3*n4) { s = c; d = oc; i -= 2*n4; }
  else               { s = e; d = oe; i -= 3*n4; }
  float4 x = ((const float4*)s)[i];
  ushort4 y;
  y.x = cvt_bf(x.x); y.y = cvt_bf(x.y); y.z = cvt_bf(x.z); y.w = cvt_bf(x.w);
  ((ushort4*)d)[i] = y;
}

// ---------------- GEMM: out = A @ W^T  (both row-major, B^T pattern) ----
// MODE 0: write bf16 [B,H,N,Dh] scaled by oscale   (Q/K projections)
// MODE 1: write bf16 [B,H,Dh,N]                    (V projection, pre-transposed)
// MODE 2: write fp32 row-major + residual          (output projection)
template<int MODE>
__global__ __launch_bounds__(256) void gemm128(
    const u16* __restrict__ A,   // [8192][1024] bf16
    const u16* __restrict__ W,   // [1024][1024] bf16 (rows = out channels)
    u16* __restrict__ obf,
    const float* __restrict__ resid,
    float* __restrict__ ofp,
    float oscale)
{
  __shared__ __align__(16) u16 As[128*32];
  __shared__ __align__(16) u16 Bs[128*32];
  const int t = threadIdx.x;
  const int lane = t & 63;
  const int w = t >> 6;
  const int wr = w >> 1, wc = w & 1;
  const int m0 = blockIdx.x * 128;
  const int n0 = blockIdx.y * 128;
  f32x4 acc[4][4] = {};

  const int r0 = t >> 2;      // staging row (+ i*64)
  const int pcb = t & 3;      // physical 8-elem col block
  const int fr = lane & 15;
  const int fg = lane >> 4;

  for (int k0 = 0; k0 < 1024; k0 += 32) {
#pragma unroll
    for (int i = 0; i < 2; ++i) {
      int r = i*64 + r0;
      int scol = k0 + ((pcb ^ (r & 3)) * 8);   // inverse-swizzled source
      gload16(A + (size_t)(m0 + r)*1024 + scol, &As[(i*256 + t)*8]);
      gload16(W + (size_t)(n0 + r)*1024 + scol, &Bs[(i*256 + t)*8]);
    }
    __syncthreads();
    bf16x8 af[4], bfr[4];
#pragma unroll
    for (int i = 0; i < 4; ++i) {
      int ra = wr*64 + i*16 + fr;
      af[i]  = *(const bf16x8*)&As[ra*32 + ((fg ^ (ra & 3)) * 8)];
      int rb = wc*64 + i*16 + fr;
      bfr[i] = *(const bf16x8*)&Bs[rb*32 + ((fg ^ (rb & 3)) * 8)];
    }
#pragma unroll
    for (int i = 0; i < 4; ++i)
#pragma unroll
      for (int j = 0; j < 4; ++j)
        acc[i][j] = __builtin_amdgcn_mfma_f32_16x16x32_bf16(af[i], bfr[j], acc[i][j], 0, 0, 0);
    __syncthreads();
  }

#pragma unroll
  for (int i = 0; i < 4; ++i) {
#pragma unroll
    for (int j = 0; j < 4; ++j) {
#pragma unroll
      for (int jj = 0; jj < 4; ++jj) {
        int row = m0 + wr*64 + i*16 + fg*4 + jj;   // verified C/D: row=(lane>>4)*4+reg
        int col = n0 + wc*64 + j*16 + fr;          //               col=lane&15
        float val = acc[i][j][jj];
        if (MODE == 0) {
          int b = row >> 11, n = row & 2047, h = col >> 6, dh = col & 63;
          obf[(((size_t)(b*H_ + h))*N_ + n)*DH_ + dh] = cvt_bf(val * oscale);
        } else if (MODE == 1) {
          int b = row >> 11, n = row & 2047, h = col >> 6, dh = col & 63;
          obf[(((size_t)(b*H_ + h))*DH_ + dh)*N_ + n] = cvt_bf(val);
        } else {
          size_t idx = (size_t)row*1024 + col;
          ofp[idx] = val + resid[idx];
        }
      }
    }
  }
}

// ---------------- flash attention, swapped-operand 32x32 ----------------
// grid (N/256, B*H); block 512 = 8 waves; wave w owns q-rows q0+w*32..+32.
// S^T = mfma32(K, Q): lane owns q = q0w + (lane&31); 32 P-values in regs.
// Q pre-scaled by QSCALE -> exp2 softmax.
__device__ __forceinline__ float vmax16(const f32x16& v) {
  float a = fmaxf(fmaxf(v[0], v[1]), fmaxf(v[2], v[3]));
  float b = fmaxf(fmaxf(v[4], v[5]), fmaxf(v[6], v[7]));
  float c = fmaxf(fmaxf(v[8], v[9]), fmaxf(v[10], v[11]));
  float d = fmaxf(fmaxf(v[12], v[13]), fmaxf(v[14], v[15]));
  return fmaxf(fmaxf(a, b), fmaxf(c, d));
}
__device__ __forceinline__ float vsum16(const f32x16& v) {
  float a = (v[0] + v[1]) + (v[2] + v[3]);
  float b = (v[4] + v[5]) + (v[6] + v[7]);
  float c = (v[8] + v[9]) + (v[10] + v[11]);
  float d = (v[12] + v[13]) + (v[14] + v[15]);
  return (a + b) + (c + d);
}
// P^T B-frag assembly from one 16-reg S subtile (T12 recipe, derived):
// words w_i = cvt_pk(S[2i],S[2i+1]); (a,a')=swap(w0,w2),(b,b')=swap(w1,w3)
// -> frag words [a,b,a',b'] = k(+0..7|+8..15) for half-waves 0|1.
__device__ __forceinline__ void buildP(const f32x16& S, bf16x8* pf) {
  unsigned w0 = cvt_pk(S[0], S[1]),  w1 = cvt_pk(S[2], S[3]);
  unsigned w2 = cvt_pk(S[4], S[5]),  w3 = cvt_pk(S[6], S[7]);
  i32x2 A2 = pl32swap(w0, w2), B2 = pl32swap(w1, w3);
  u32x4 f0 = { (unsigned)A2.x, (unsigned)B2.x, (unsigned)A2.y, (unsigned)B2.y };
  pf[0] = __builtin_bit_cast(bf16x8, f0);
  unsigned w4 = cvt_pk(S[8], S[9]),   w5 = cvt_pk(S[10], S[11]);
  unsigned w6 = cvt_pk(S[12], S[13]), w7 = cvt_pk(S[14], S[15]);
  i32x2 C2 = pl32swap(w4, w6), D2 = pl32swap(w5, w7);
  u32x4 f1 = { (unsigned)C2.x, (unsigned)D2.x, (unsigned)C2.y, (unsigned)D2.y };
  pf[1] = __builtin_bit_cast(bf16x8, f1);
}

__global__ __launch_bounds__(512, 4) void flash_attn(
    const u16* __restrict__ Qs, const u16* __restrict__ Ks,
    const u16* __restrict__ VTs, u16* __restrict__ ctx)
{
  __shared__ __align__(16) u16 Klds[2][64*64];
  __shared__ __align__(16) u16 Vlds[2][64*64];
  const int t = threadIdx.x;
  const int lane = t & 63;
  const int w = t >> 6;         // 0..7
  const int l31 = lane & 31;
  const int h = lane >> 5;      // half-wave
  const int q0 = blockIdx.x * 256 + w * 32;
  const int bh = blockIdx.y;
  const u16* Qbh = Qs  + (size_t)bh * N_ * DH_;
  const u16* Kbh = Ks  + (size_t)bh * N_ * DH_;
  const u16* Vbh = VTs + (size_t)bh * DH_ * N_;

  // Q B-frags: qf[dd] = Q[q0+l31][dd*16 + h*8 + 0..7]
  bf16x8 qf[4];
#pragma unroll
  for (int dd = 0; dd < 4; ++dd)
    qf[dd] = *(const bf16x8*)&Qbh[(size_t)(q0 + l31)*64 + dd*16 + h*8];

  float m = -1e30f, lp = 0.f;
  f32x16 O0 = {}, O1 = {};

  // staging: thread -> (row sr, colblock scb); inverse-swizzled source col
  const int sr = t >> 3;
  const int kcb = (t & 7) ^ (sr & 7);
  const u16* ksrc = Kbh + (size_t)sr*64 + kcb*8;      // advances 64*64 per tile
  const u16* vsrc = Vbh + (size_t)sr*N_ + kcb*8;      // advances 64 per tile

  auto stage = [&](int buf, int kv) {
    gload16(ksrc + (size_t)kv*64, &Klds[buf][t*8]);
    gload16(vsrc + kv,            &Vlds[buf][t*8]);
  };

  // fragment-read LDS offsets (u16 units), loop-invariant
  const int krow = l31;            // + 32*sub
  const int ks7 = krow & 7;

  stage(0, 0);
  __syncthreads();
  int cur = 0;

  for (int kv0 = 0; kv0 < N_; kv0 += 64) {
    if (kv0 + 64 < N_) stage(cur ^ 1, kv0 + 64);

    // S^T[k][q] = sum_d K[k][d] Q[q][d] ; chain d in 4 mfmas, 2 k-subtiles
    f32x16 S0 = {}, S1 = {};
#pragma unroll
    for (int dd = 0; dd < 4; ++dd) {
      int cb = ((2*dd + h) ^ ks7) * 8;
      bf16x8 kf0 = *(const bf16x8*)&Klds[cur][krow*64 + cb];
      bf16x8 kf1 = *(const bf16x8*)&Klds[cur][(32 + krow)*64 + cb];
      S0 = __builtin_amdgcn_mfma_f32_32x32x16_bf16(kf0, qf[dd], S0, 0, 0, 0);
      S1 = __builtin_amdgcn_mfma_f32_32x32x16_bf16(kf1, qf[dd], S1, 0, 0, 0);
    }

    // online softmax: all 32 k-values lane-local (for q = q0+l31)
    float pm = fmaxf(vmax16(S0), vmax16(S1));
    i32x2 msw = pl32swap(__float_as_uint(pm), __float_as_uint(pm));
    pm = fmaxf(__uint_as_float((unsigned)msw.x), __uint_as_float((unsigned)msw.y));
    if (!__all(pm <= m + 8.f)) {          // T13 defer-max, wave-uniform
      float mn = fmaxf(m, pm);
      float al = __builtin_amdgcn_exp2f(m - mn);
      m = mn;
      lp *= al;
#pragma unroll
      for (int r = 0; r < 16; ++r) { O0[r] *= al; O1[r] *= al; }
    }
#pragma unroll
    for (int r = 0; r < 16; ++r) {
      S0[r] = __builtin_amdgcn_exp2f(S0[r] - m);
      S1[r] = __builtin_amdgcn_exp2f(S1[r] - m);
    }
    lp += vsum16(S0) + vsum16(S1);

    // P^T B-frags in-register (16 cvt_pk + 8 permlane32_swap)
    bf16x8 pf[4];
    buildP(S0, &pf[0]);
    buildP(S1, &pf[2]);

    // O^T[d][q] += sum_k V^T[d][k] P^T[k][q]
#pragma unroll
    for (int ks = 0; ks < 4; ++ks) {
      int cb = ((2*ks + h) ^ ks7) * 8;
      bf16x8 vf0 = *(const bf16x8*)&Vlds[cur][krow*64 + cb];
      bf16x8 vf1 = *(const bf16x8*)&Vlds[cur][(32 + krow)*64 + cb];
      O0 = __builtin_amdgcn_mfma_f32_32x32x16_bf16(vf0, pf[ks], O0, 0, 0, 0);
      O1 = __builtin_amdgcn_mfma_f32_32x32x16_bf16(vf1, pf[ks], O1, 0, 0, 0);
    }

    __syncthreads();   // all waves done with [cur]; prefetch [cur^1] landed
    cur ^= 1;
  }

  // combine half-wave l, invert
  i32x2 lsw = pl32swap(__float_as_uint(lp), __float_as_uint(lp));
  float ltot = __uint_as_float((unsigned)lsw.x) + __uint_as_float((unsigned)lsw.y);
  float linv = __builtin_amdgcn_rcpf(ltot);

  // write ctx [B,N,D] bf16; lane q = q0+l31 holds d = (r&3)+8*(r>>2)+4h+32dt
  int b = bh >> 4, hh = bh & 15;
  u32x4* dummy; (void)dummy;
  unsigned* crow = (unsigned*)(ctx + ((size_t)b*N_ + (q0 + l31))*D_ + hh*64);
#pragma unroll
  for (int rp = 0; rp < 8; ++rp) {
    int r = rp*2;
    int d0 = (r & 3) + 8*(r >> 2) + 4*h;
    crow[d0 >> 1]        = cvt_pk(O0[r]*linv, O0[r+1]*linv);
    crow[(d0 + 32) >> 1] = cvt_pk(O1[r]*linv, O1[r+1]*linv);
  }
}

// ---------------- LayerNorm in-place on d_out ----------------
__global__ __launch_bounds__(256) void ln_fwd(float* __restrict__ io,
    const float* __restrict__ gamma, const float* __restrict__ beta)
{
  __shared__ float red[4];
  const int t = threadIdx.x;
  const int lane = t & 63, w = t >> 6;
  float4* row = (float4*)(io + (size_t)blockIdx.x * 1024);
  float4 x = row[t];
  float s = x.x + x.y + x.z + x.w;
#pragma unroll
  for (int m = 1; m < 64; m <<= 1) s += __shfl_xor(s, m);
  if (lane == 0) red[w] = s;
  __syncthreads();
  float mean = (red[0] + red[1] + red[2] + red[3]) * (1.f/1024.f);
  __syncthreads();
  float dx0 = x.x - mean, dx1 = x.y - mean, dx2 = x.z - mean, dx3 = x.w - mean;
  float sq = dx0*dx0 + dx1*dx1 + dx2*dx2 + dx3*dx3;
#pragma unroll
  for (int m = 1; m < 64; m <<= 1) sq += __shfl_xor(sq, m);
  if (lane == 0) red[w] = sq;
  __syncthreads();
  float var = (red[0] + red[1] + red[2] + red[3]) * (1.f/1024.f);
  float rstd = rsqrtf(var + 1e-5f);
  float4 g = ((const float4*)gamma)[t];
  float4 bb = ((const float4*)beta)[t];
  float4 y;
  y.x = dx0*rstd*g.x + bb.x;
  y.y = dx1*rstd*g.y + bb.y;
  y.z = dx2*rstd*g.z + bb.z;
  y.w = dx3*rstd*g.w + bb.w;
  row[t] = y;
}

extern "C" void kernel_launch(void* const* d_in, const int* in_sizes, int n_in,
                              void* d_out, int out_size, void* d_ws, size_t ws_size,
                              hipStream_t stream) {
  const float* q     = (const float*)d_in[0];
  const float* k     = (const float*)d_in[1];
  const float* v     = (const float*)d_in[2];
  const float* Wq    = (const float*)d_in[3];
  const float* Wk    = (const float*)d_in[4];
  const float* Wv    = (const float*)d_in[5];
  const float* Wo    = (const float*)d_in[6];
  const float* gamma = (const float*)d_in[7];
  const float* beta  = (const float*)d_in[8];
  float* out = (float*)d_out;

  char* ws = (char*)d_ws;
  const size_t MB = 1024*1024;
  u16* qb  = (u16*)(ws + 0*MB);    // 16 MB each
  u16* kb  = (u16*)(ws + 16*MB);
  u16* vb  = (u16*)(ws + 32*MB);
  u16* Wqb = (u16*)(ws + 48*MB);   // 2 MB each
  u16* Wkb = (u16*)(ws + 50*MB);
  u16* Wvb = (u16*)(ws + 52*MB);
  u16* Wob = (u16*)(ws + 54*MB);
  u16* Qs  = (u16*)(ws + 56*MB);   // [B,H,N,Dh] bf16 (pre-scaled by QSCALE)
  u16* Ks  = (u16*)(ws + 72*MB);   // [B,H,N,Dh]
  u16* VTs = (u16*)(ws + 88*MB);   // [B,H,Dh,N]
  u16* ctx = (u16*)(ws + 0*MB);    // reuse qb region after Q-proj

  const int n4big = (B_*N_*D_)/4;  // 2M float4s
  const int n4w   = (D_*D_)/4;     // 256K
  cast_qkv<<<3*n4big/256, 256, 0, stream>>>(q, k, v, qb, kb, vb);
  cast_w4<<<4*n4w/256, 256, 0, stream>>>(Wq, Wk, Wv, Wo, Wqb, Wkb, Wvb, Wob);

  dim3 gproj(M_/128, D_/128);   // (64, 8)
  gemm128<0><<<gproj, 256, 0, stream>>>(qb, Wqb, Qs,  nullptr, nullptr, QSCALE);
  gemm128<0><<<gproj, 256, 0, stream>>>(kb, Wkb, Ks,  nullptr, nullptr, 1.0f);
  gemm128<1><<<gproj, 256, 0, stream>>>(vb, Wvb, VTs, nullptr, nullptr, 1.0f);

  flash_attn<<<dim3(N_/256, B_*H_), 512, 0, stream>>>(Qs, Ks, VTs, ctx);

  gemm128<2><<<gproj, 256, 0, stream>>>(ctx, Wob, nullptr, q, out, 1.0f);

  ln_fwd<<<M_, 256, 0, stream>>>(out, gamma, beta);
}

// Round 4
// 232.025 us; speedup vs baseline: 1.6157x; 1.0553x over previous
//
#include <hip/hip_runtime.h>
#include <cstdint>
#include <math.h>

typedef __bf16 bf16x8 __attribute__((ext_vector_type(8)));
typedef float f32x4 __attribute__((ext_vector_type(4)));
typedef float f32x16 __attribute__((ext_vector_type(16)));
typedef int i32x2 __attribute__((ext_vector_type(2)));
typedef unsigned u32x4 __attribute__((ext_vector_type(4)));
typedef unsigned short u16;

#define B_ 4
#define N_ 2048
#define D_ 1024
#define H_ 16
#define DH_ 64
#define M_ (B_*N_)   // 8192

#define QSCALE (0.125f * 1.44269504088896f)   // 1/sqrt(Dh) * log2(e)

typedef const void __attribute__((address_space(1))) gvoid;
typedef void __attribute__((address_space(3))) lvoid;

__device__ __forceinline__ void gload16(const void* g, void* l) {
  __builtin_amdgcn_global_load_lds((gvoid*)g, (lvoid*)l, 16, 0, 0);
}

// hardware bf16 convert — do NOT hand-roll RNE (m240)
__device__ __forceinline__ u16 cvt_bf(float f) {
  __bf16 h = (__bf16)f;
  return *(u16*)&h;
}

// v_cvt_pk_bf16_f32: word = [bf16(lo) | bf16(hi)<<16]  (no builtin on gfx950)
__device__ __forceinline__ unsigned cvt_pk(float lo, float hi) {
  unsigned r;
  asm("v_cvt_pk_bf16_f32 %0, %1, %2" : "=v"(r) : "v"(lo), "v"(hi));
  return r;
}

__device__ __forceinline__ i32x2 pl32swap(unsigned a, unsigned b) {
  return __builtin_amdgcn_permlane32_swap((int)a, (int)b, false, false);
}

// ---------------- one fused cast kernel: 3 big (q,k,v) + 4 weights -------
__global__ __launch_bounds__(256) void cast_all(
    const float* __restrict__ q, const float* __restrict__ k, const float* __restrict__ v,
    const float* __restrict__ wq, const float* __restrict__ wk,
    const float* __restrict__ wv, const float* __restrict__ wo,
    u16* __restrict__ oq, u16* __restrict__ ok, u16* __restrict__ ov,
    u16* __restrict__ owq, u16* __restrict__ owk, u16* __restrict__ owv, u16* __restrict__ owo) {
  const int nb = (B_*N_*D_)/4;   // 2M
  const int nw = (D_*D_)/4;      // 256K
  int i = blockIdx.x * 256 + threadIdx.x;
  const float* s; u16* d;
  if (i < 3*nb) {
    if (i < nb)        { s = q; d = oq; }
    else if (i < 2*nb) { s = k; d = ok; i -= nb; }
    else               { s = v; d = ov; i -= 2*nb; }
  } else {
    i -= 3*nb;
    if (i < nw)        { s = wq; d = owq; }
    else if (i < 2*nw) { s = wk; d = owk; i -= nw; }
    else if (i < 3*nw) { s = wv; d = owv; i -= 2*nw; }
    else               { s = wo; d = owo; i -= 3*nw; }
  }
  float4 x = ((const float4*)s)[i];
  ushort4 y;
  y.x = cvt_bf(x.x); y.y = cvt_bf(x.y); y.z = cvt_bf(x.z); y.w = cvt_bf(x.w);
  ((ushort4*)d)[i] = y;
}

// ---------------- QKV projection GEMM, BK=64, fused z=3 ------------------
// out = A @ W^T. z=0: Q (scaled, [B,H,N,Dh]); z=1: K ([B,H,N,Dh]);
// z=2: V pre-transposed ([B,H,Dh,N]).
__global__ __launch_bounds__(256) void gemm_qkv(
    const u16* __restrict__ Aq, const u16* __restrict__ Ak, const u16* __restrict__ Av,
    const u16* __restrict__ Wq, const u16* __restrict__ Wk, const u16* __restrict__ Wv,
    u16* __restrict__ Oq, u16* __restrict__ Ok, u16* __restrict__ Ov)
{
  __shared__ __align__(16) u16 As[128*64];
  __shared__ __align__(16) u16 Bs[128*64];
  const int z = blockIdx.z;
  const u16* A = (z == 0) ? Aq : (z == 1) ? Ak : Av;
  const u16* W = (z == 0) ? Wq : (z == 1) ? Wk : Wv;
  u16* obf     = (z == 0) ? Oq : (z == 1) ? Ok : Ov;
  const float oscale = (z == 0) ? QSCALE : 1.0f;

  const int t = threadIdx.x;
  const int lane = t & 63;
  const int w = t >> 6;
  const int wr = w >> 1, wc = w & 1;
  const int m0 = blockIdx.x * 128;
  const int n0 = blockIdx.y * 128;
  f32x4 acc[4][4] = {};

  const int srow = t >> 3;              // + p*32
  const int scb = (t & 7) ^ (srow & 7); // swizzled colblock (p*32 ≡ 0 mod 8)
  const int fr = lane & 15;
  const int fg = lane >> 4;
  const int fs7 = fr & 7;

  for (int k0 = 0; k0 < 1024; k0 += 64) {
#pragma unroll
    for (int p = 0; p < 4; ++p) {
      int r = p*32 + srow;
      gload16(A + (size_t)(m0 + r)*1024 + k0 + scb*8, &As[(p*256 + t)*8]);
      gload16(W + (size_t)(n0 + r)*1024 + k0 + scb*8, &Bs[(p*256 + t)*8]);
    }
    __syncthreads();
#pragma unroll
    for (int ks = 0; ks < 2; ++ks) {
      bf16x8 af[4], bfr[4];
#pragma unroll
      for (int i = 0; i < 4; ++i) {
        int ra = wr*64 + i*16 + fr;
        af[i]  = *(const bf16x8*)&As[ra*64 + (((ks*4 + fg) ^ fs7) * 8)];
        int rb = wc*64 + i*16 + fr;
        bfr[i] = *(const bf16x8*)&Bs[rb*64 + (((ks*4 + fg) ^ fs7) * 8)];
      }
#pragma unroll
      for (int i = 0; i < 4; ++i)
#pragma unroll
        for (int j = 0; j < 4; ++j)
          acc[i][j] = __builtin_amdgcn_mfma_f32_16x16x32_bf16(af[i], bfr[j], acc[i][j], 0, 0, 0);
    }
    __syncthreads();
  }

#pragma unroll
  for (int i = 0; i < 4; ++i) {
#pragma unroll
    for (int j = 0; j < 4; ++j) {
#pragma unroll
      for (int jj = 0; jj < 4; ++jj) {
        int row = m0 + wr*64 + i*16 + fg*4 + jj;   // verified C/D layout
        int col = n0 + wc*64 + j*16 + fr;
        float val = acc[i][j][jj];
        int b = row >> 11, n = row & 2047, h = col >> 6, dh = col & 63;
        if (z != 2) {
          obf[(((size_t)(b*H_ + h))*N_ + n)*DH_ + dh] = cvt_bf(val * oscale);
        } else {
          obf[(((size_t)(b*H_ + h))*DH_ + dh)*N_ + n] = cvt_bf(val);
        }
      }
    }
  }
}

// ---------------- output projection GEMM + residual, BK=64 ---------------
__global__ __launch_bounds__(256) void gemm_out(
    const u16* __restrict__ A, const u16* __restrict__ W,
    const float* __restrict__ resid, float* __restrict__ ofp)
{
  __shared__ __align__(16) u16 As[128*64];
  __shared__ __align__(16) u16 Bs[128*64];
  const int t = threadIdx.x;
  const int lane = t & 63;
  const int w = t >> 6;
  const int wr = w >> 1, wc = w & 1;
  const int m0 = blockIdx.x * 128;
  const int n0 = blockIdx.y * 128;
  f32x4 acc[4][4] = {};

  const int srow = t >> 3;
  const int scb = (t & 7) ^ (srow & 7);
  const int fr = lane & 15;
  const int fg = lane >> 4;
  const int fs7 = fr & 7;

  for (int k0 = 0; k0 < 1024; k0 += 64) {
#pragma unroll
    for (int p = 0; p < 4; ++p) {
      int r = p*32 + srow;
      gload16(A + (size_t)(m0 + r)*1024 + k0 + scb*8, &As[(p*256 + t)*8]);
      gload16(W + (size_t)(n0 + r)*1024 + k0 + scb*8, &Bs[(p*256 + t)*8]);
    }
    __syncthreads();
#pragma unroll
    for (int ks = 0; ks < 2; ++ks) {
      bf16x8 af[4], bfr[4];
#pragma unroll
      for (int i = 0; i < 4; ++i) {
        int ra = wr*64 + i*16 + fr;
        af[i]  = *(const bf16x8*)&As[ra*64 + (((ks*4 + fg) ^ fs7) * 8)];
        int rb = wc*64 + i*16 + fr;
        bfr[i] = *(const bf16x8*)&Bs[rb*64 + (((ks*4 + fg) ^ fs7) * 8)];
      }
#pragma unroll
      for (int i = 0; i < 4; ++i)
#pragma unroll
        for (int j = 0; j < 4; ++j)
          acc[i][j] = __builtin_amdgcn_mfma_f32_16x16x32_bf16(af[i], bfr[j], acc[i][j], 0, 0, 0);
    }
    __syncthreads();
  }

#pragma unroll
  for (int i = 0; i < 4; ++i)
#pragma unroll
    for (int j = 0; j < 4; ++j)
#pragma unroll
      for (int jj = 0; jj < 4; ++jj) {
        int row = m0 + wr*64 + i*16 + fg*4 + jj;
        int col = n0 + wc*64 + j*16 + fr;
        size_t idx = (size_t)row*1024 + col;
        ofp[idx] = acc[i][j][jj] + resid[idx];
      }
}

// ---------------- flash attention, swapped-operand 32x32, KVBLK=128 ------
// grid (B*H=64, N/256=8): all q-blocks of one bh land on one XCD (flat%8).
// block 512 = 8 waves; wave w owns q-rows q0+w*32..+32.
// S^T = mfma32(K, Q): lane owns q = q0w + (lane&31); P lane-local.
__device__ __forceinline__ float vmax16(const f32x16& v) {
  float a = fmaxf(fmaxf(v[0], v[1]), fmaxf(v[2], v[3]));
  float b = fmaxf(fmaxf(v[4], v[5]), fmaxf(v[6], v[7]));
  float c = fmaxf(fmaxf(v[8], v[9]), fmaxf(v[10], v[11]));
  float d = fmaxf(fmaxf(v[12], v[13]), fmaxf(v[14], v[15]));
  return fmaxf(fmaxf(a, b), fmaxf(c, d));
}
__device__ __forceinline__ float vsum16(const f32x16& v) {
  float a = (v[0] + v[1]) + (v[2] + v[3]);
  float b = (v[4] + v[5]) + (v[6] + v[7]);
  float c = (v[8] + v[9]) + (v[10] + v[11]);
  float d = (v[12] + v[13]) + (v[14] + v[15]);
  return (a + b) + (c + d);
}
// P^T B-frag assembly (T12): pf[0] = k 0..15, pf[1] = k 16..31 of S's chunk
__device__ __forceinline__ void buildP(const f32x16& S, bf16x8* pf) {
  unsigned w0 = cvt_pk(S[0], S[1]),  w1 = cvt_pk(S[2], S[3]);
  unsigned w2 = cvt_pk(S[4], S[5]),  w3 = cvt_pk(S[6], S[7]);
  i32x2 A2 = pl32swap(w0, w2), B2 = pl32swap(w1, w3);
  u32x4 f0 = { (unsigned)A2.x, (unsigned)B2.x, (unsigned)A2.y, (unsigned)B2.y };
  pf[0] = __builtin_bit_cast(bf16x8, f0);
  unsigned w4 = cvt_pk(S[8], S[9]),   w5 = cvt_pk(S[10], S[11]);
  unsigned w6 = cvt_pk(S[12], S[13]), w7 = cvt_pk(S[14], S[15]);
  i32x2 C2 = pl32swap(w4, w6), D2 = pl32swap(w5, w7);
  u32x4 f1 = { (unsigned)C2.x, (unsigned)D2.x, (unsigned)C2.y, (unsigned)D2.y };
  pf[1] = __builtin_bit_cast(bf16x8, f1);
}

__global__ __launch_bounds__(512, 2) void flash_attn(
    const u16* __restrict__ Qs, const u16* __restrict__ Ks,
    const u16* __restrict__ VTs, u16* __restrict__ ctx)
{
  __shared__ __align__(16) u16 Klds[2][128*64];   // [k 0..127][d 0..63]
  __shared__ __align__(16) u16 Vlds[2][64*128];   // [d 0..63][k 0..127]
  const int t = threadIdx.x;
  const int lane = t & 63;
  const int w = t >> 6;         // 0..7
  const int l31 = lane & 31;
  const int h = lane >> 5;      // half-wave
  const int bh = blockIdx.x;
  const int q0 = blockIdx.y * 256 + w * 32;
  const u16* Qbh = Qs  + (size_t)bh * N_ * DH_;
  const u16* Kbh = Ks  + (size_t)bh * N_ * DH_;
  const u16* Vbh = VTs + (size_t)bh * DH_ * N_;

  // Q B-frags: qf[dd] = Q[q0+l31][dd*16 + h*8 + 0..7]
  bf16x8 qf[4];
#pragma unroll
  for (int dd = 0; dd < 4; ++dd)
    qf[dd] = *(const bf16x8*)&Qbh[(size_t)(q0 + l31)*64 + dd*16 + h*8];

  float m = -1e30f, lp = 0.f;
  f32x16 O0 = {}, O1 = {};

  // staging (2 passes of 512 threads per matrix per tile)
  const int krow0 = t >> 3;                       // + p*64
  const int kcb   = (t & 7) ^ ((t >> 3) & 7);
  const int vrow0 = t >> 4;                       // + p*32
  const int vcb   = (t & 15) ^ ((t >> 4) & 7);
  const u16* ksrc = Kbh + (size_t)krow0*64 + kcb*8;   // + kv*64
  const u16* vsrc = Vbh + (size_t)vrow0*N_ + vcb*8;   // + kv

  auto stage = [&](int buf, int kv) {
#pragma unroll
    for (int p = 0; p < 2; ++p) {
      gload16(ksrc + (size_t)(kv + p*64)*64, &Klds[buf][(p*512 + t)*8]);
      gload16(vsrc + kv + (size_t)(p*32)*N_, &Vlds[buf][(p*512 + t)*8]);
    }
  };

  const int l7 = l31 & 7;

  stage(0, 0);
  __syncthreads();
  int cur = 0;

  for (int kv0 = 0; kv0 < N_; kv0 += 128) {
    if (kv0 + 128 < N_) stage(cur ^ 1, kv0 + 128);

#pragma unroll
    for (int half = 0; half < 2; ++half) {
      const int kb = half * 64;
      // S^T[k][q]: A = K rows (kb + s*32 + l31), mfma-k = d
      f32x16 S0 = {}, S1 = {};
      __builtin_amdgcn_s_setprio(1);
#pragma unroll
      for (int dd = 0; dd < 4; ++dd) {
        int cb = ((2*dd + h) ^ l7) * 8;
        bf16x8 kf0 = *(const bf16x8*)&Klds[cur][(kb + l31)*64 + cb];
        bf16x8 kf1 = *(const bf16x8*)&Klds[cur][(kb + 32 + l31)*64 + cb];
        S0 = __builtin_amdgcn_mfma_f32_32x32x16_bf16(kf0, qf[dd], S0, 0, 0, 0);
        S1 = __builtin_amdgcn_mfma_f32_32x32x16_bf16(kf1, qf[dd], S1, 0, 0, 0);
      }
      __builtin_amdgcn_s_setprio(0);

      // online softmax on this 64-k chunk (all lane-local)
      float pm = fmaxf(vmax16(S0), vmax16(S1));
      i32x2 msw = pl32swap(__float_as_uint(pm), __float_as_uint(pm));
      pm = fmaxf(__uint_as_float((unsigned)msw.x), __uint_as_float((unsigned)msw.y));
      if (!__all(pm <= m + 8.f)) {          // T13 defer-max
        float mn = fmaxf(m, pm);
        float al = __builtin_amdgcn_exp2f(m - mn);
        m = mn;
        lp *= al;
#pragma unroll
        for (int r = 0; r < 16; ++r) { O0[r] *= al; O1[r] *= al; }
      }
#pragma unroll
      for (int r = 0; r < 16; ++r) {
        S0[r] = __builtin_amdgcn_exp2f(S0[r] - m);
        S1[r] = __builtin_amdgcn_exp2f(S1[r] - m);
      }
      lp += vsum16(S0) + vsum16(S1);

      bf16x8 pf[4];
      buildP(S0, &pf[0]);
      buildP(S1, &pf[2]);

      // O^T[d][q] += V^T[d][k-chunk] P^T
      __builtin_amdgcn_s_setprio(1);
#pragma unroll
      for (int ks = 0; ks < 4; ++ks) {
        int cb = ((half*8 + ks*2 + h) ^ l7) * 8;
        bf16x8 vf0 = *(const bf16x8*)&Vlds[cur][l31*128 + cb];
        bf16x8 vf1 = *(const bf16x8*)&Vlds[cur][(32 + l31)*128 + cb];
        O0 = __builtin_amdgcn_mfma_f32_32x32x16_bf16(vf0, pf[ks], O0, 0, 0, 0);
        O1 = __builtin_amdgcn_mfma_f32_32x32x16_bf16(vf1, pf[ks], O1, 0, 0, 0);
      }
      __builtin_amdgcn_s_setprio(0);
    }

    __syncthreads();   // all waves done with [cur]; prefetch landed
    cur ^= 1;
  }

  // combine half-wave l, invert
  i32x2 lsw = pl32swap(__float_as_uint(lp), __float_as_uint(lp));
  float ltot = __uint_as_float((unsigned)lsw.x) + __uint_as_float((unsigned)lsw.y);
  float linv = __builtin_amdgcn_rcpf(ltot);

  // write ctx [B,N,D] bf16; lane q = q0+l31 holds d = (r&3)+8*(r>>2)+4h (+32)
  int b = bh >> 4, hh = bh & 15;
  unsigned* crow = (unsigned*)(ctx + ((size_t)b*N_ + (q0 + l31))*D_ + hh*64);
#pragma unroll
  for (int rp = 0; rp < 8; ++rp) {
    int r = rp*2;
    int d0 = (r & 3) + 8*(r >> 2) + 4*h;
    crow[d0 >> 1]        = cvt_pk(O0[r]*linv, O0[r+1]*linv);
    crow[(d0 + 32) >> 1] = cvt_pk(O1[r]*linv, O1[r+1]*linv);
  }
}

// ---------------- LayerNorm in-place on d_out ----------------
__global__ __launch_bounds__(256) void ln_fwd(float* __restrict__ io,
    const float* __restrict__ gamma, const float* __restrict__ beta)
{
  __shared__ float red[4];
  const int t = threadIdx.x;
  const int lane = t & 63, w = t >> 6;
  float4* row = (float4*)(io + (size_t)blockIdx.x * 1024);
  float4 x = row[t];
  float s = x.x + x.y + x.z + x.w;
#pragma unroll
  for (int m = 1; m < 64; m <<= 1) s += __shfl_xor(s, m);
  if (lane == 0) red[w] = s;
  __syncthreads();
  float mean = (red[0] + red[1] + red[2] + red[3]) * (1.f/1024.f);
  __syncthreads();
  float dx0 = x.x - mean, dx1 = x.y - mean, dx2 = x.z - mean, dx3 = x.w - mean;
  float sq = dx0*dx0 + dx1*dx1 + dx2*dx2 + dx3*dx3;
#pragma unroll
  for (int m = 1; m < 64; m <<= 1) sq += __shfl_xor(sq, m);
  if (lane == 0) red[w] = sq;
  __syncthreads();
  float var = (red[0] + red[1] + red[2] + red[3]) * (1.f/1024.f);
  float rstd = rsqrtf(var + 1e-5f);
  float4 g = ((const float4*)gamma)[t];
  float4 bb = ((const float4*)beta)[t];
  float4 y;
  y.x = dx0*rstd*g.x + bb.x;
  y.y = dx1*rstd*g.y + bb.y;
  y.z = dx2*rstd*g.z + bb.z;
  y.w = dx3*rstd*g.w + bb.w;
  row[t] = y;
}

extern "C" void kernel_launch(void* const* d_in, const int* in_sizes, int n_in,
                              void* d_out, int out_size, void* d_ws, size_t ws_size,
                              hipStream_t stream) {
  const float* q     = (const float*)d_in[0];
  const float* k     = (const float*)d_in[1];
  const float* v     = (const float*)d_in[2];
  const float* Wq    = (const float*)d_in[3];
  const float* Wk    = (const float*)d_in[4];
  const float* Wv    = (const float*)d_in[5];
  const float* Wo    = (const float*)d_in[6];
  const float* gamma = (const float*)d_in[7];
  const float* beta  = (const float*)d_in[8];
  float* out = (float*)d_out;

  char* ws = (char*)d_ws;
  const size_t MB = 1024*1024;
  u16* qb  = (u16*)(ws + 0*MB);    // 16 MB each
  u16* kb  = (u16*)(ws + 16*MB);
  u16* vb  = (u16*)(ws + 32*MB);
  u16* Wqb = (u16*)(ws + 48*MB);   // 2 MB each
  u16* Wkb = (u16*)(ws + 50*MB);
  u16* Wvb = (u16*)(ws + 52*MB);
  u16* Wob = (u16*)(ws + 54*MB);
  u16* Qs  = (u16*)(ws + 56*MB);   // [B,H,N,Dh] bf16 (pre-scaled by QSCALE)
  u16* Ks  = (u16*)(ws + 72*MB);   // [B,H,N,Dh]
  u16* VTs = (u16*)(ws + 88*MB);   // [B,H,Dh,N]
  u16* ctx = (u16*)(ws + 0*MB);    // reuse qb region after Q-proj

  const int ntot4 = 3*((B_*N_*D_)/4) + 4*((D_*D_)/4);   // 7M
  cast_all<<<ntot4/256, 256, 0, stream>>>(q, k, v, Wq, Wk, Wv, Wo,
                                          qb, kb, vb, Wqb, Wkb, Wvb, Wob);

  dim3 gproj(M_/128, D_/128, 3);   // (64, 8, 3)
  gemm_qkv<<<gproj, 256, 0, stream>>>(qb, kb, vb, Wqb, Wkb, Wvb, Qs, Ks, VTs);

  flash_attn<<<dim3(B_*H_, N_/256), 512, 0, stream>>>(Qs, Ks, VTs, ctx);

  gemm_out<<<dim3(M_/128, D_/128), 256, 0, stream>>>(ctx, Wob, q, out);

  ln_fwd<<<M_, 256, 0, stream>>>(out, gamma, beta);
}

// Round 5
// 231.328 us; speedup vs baseline: 1.6206x; 1.0030x over previous
//
#include <hip/hip_runtime.h>
#include <cstdint>
#include <math.h>

typedef __bf16 bf16x8 __attribute__((ext_vector_type(8)));
typedef float f32x2 __attribute__((ext_vector_type(2)));
typedef float f32x4 __attribute__((ext_vector_type(4)));
typedef float f32x16 __attribute__((ext_vector_type(16)));
typedef int i32x2 __attribute__((ext_vector_type(2)));
typedef unsigned u32x4 __attribute__((ext_vector_type(4)));
typedef unsigned short u16;

#define B_ 4
#define N_ 2048
#define D_ 1024
#define H_ 16
#define DH_ 64
#define M_ (B_*N_)   // 8192

#define QSCALE (0.125f * 1.44269504088896f)   // 1/sqrt(Dh) * log2(e)

typedef const void __attribute__((address_space(1))) gvoid;
typedef void __attribute__((address_space(3))) lvoid;

__device__ __forceinline__ void gload16(const void* g, void* l) {
  __builtin_amdgcn_global_load_lds((gvoid*)g, (lvoid*)l, 16, 0, 0);
}

// hardware bf16 convert — do NOT hand-roll RNE (m240)
__device__ __forceinline__ u16 cvt_bf(float f) {
  __bf16 h = (__bf16)f;
  return *(u16*)&h;
}

// v_cvt_pk_bf16_f32: word = [bf16(lo) | bf16(hi)<<16]  (no builtin on gfx950)
__device__ __forceinline__ unsigned cvt_pk(float lo, float hi) {
  unsigned r;
  asm("v_cvt_pk_bf16_f32 %0, %1, %2" : "=v"(r) : "v"(lo), "v"(hi));
  return r;
}

__device__ __forceinline__ i32x2 pl32swap(unsigned a, unsigned b) {
  return __builtin_amdgcn_permlane32_swap((int)a, (int)b, false, false);
}

// packed f32 math (VOP3P, gfx90a+): halves VALU instr count on pairs
__device__ __forceinline__ f32x2 pk_add(f32x2 a, f32x2 b) {
  f32x2 d;
  asm("v_pk_add_f32 %0, %1, %2" : "=v"(d) : "v"(a), "v"(b));
  return d;
}
__device__ __forceinline__ f32x2 pk_mul(f32x2 a, f32x2 b) {
  f32x2 d;
  asm("v_pk_mul_f32 %0, %1, %2" : "=v"(d) : "v"(a), "v"(b));
  return d;
}
// 3-input max (compiler folds to v_max3_f32)
__device__ __forceinline__ float m3(float a, float b, float c) {
  return fmaxf(fmaxf(a, b), c);
}

// ---------------- one fused cast kernel: 3 big (q,k,v) + 4 weights -------
__global__ __launch_bounds__(256) void cast_all(
    const float* __restrict__ q, const float* __restrict__ k, const float* __restrict__ v,
    const float* __restrict__ wq, const float* __restrict__ wk,
    const float* __restrict__ wv, const float* __restrict__ wo,
    u16* __restrict__ oq, u16* __restrict__ ok, u16* __restrict__ ov,
    u16* __restrict__ owq, u16* __restrict__ owk, u16* __restrict__ owv, u16* __restrict__ owo) {
  const int nb = (B_*N_*D_)/4;   // 2M
  const int nw = (D_*D_)/4;      // 256K
  int i = blockIdx.x * 256 + threadIdx.x;
  const float* s; u16* d;
  if (i < 3*nb) {
    if (i < nb)        { s = q; d = oq; }
    else if (i < 2*nb) { s = k; d = ok; i -= nb; }
    else               { s = v; d = ov; i -= 2*nb; }
  } else {
    i -= 3*nb;
    if (i < nw)        { s = wq; d = owq; }
    else if (i < 2*nw) { s = wk; d = owk; i -= nw; }
    else if (i < 3*nw) { s = wv; d = owv; i -= 2*nw; }
    else               { s = wo; d = owo; i -= 3*nw; }
  }
  float4 x = ((const float4*)s)[i];
  ushort4 y;
  y.x = cvt_bf(x.x); y.y = cvt_bf(x.y); y.z = cvt_bf(x.z); y.w = cvt_bf(x.w);
  ((ushort4*)d)[i] = y;
}

// ---------------- QKV projection GEMM, BK=64, fused z=3 ------------------
__global__ __launch_bounds__(256) void gemm_qkv(
    const u16* __restrict__ Aq, const u16* __restrict__ Ak, const u16* __restrict__ Av,
    const u16* __restrict__ Wq, const u16* __restrict__ Wk, const u16* __restrict__ Wv,
    u16* __restrict__ Oq, u16* __restrict__ Ok, u16* __restrict__ Ov)
{
  __shared__ __align__(16) u16 As[128*64];
  __shared__ __align__(16) u16 Bs[128*64];
  const int z = blockIdx.z;
  const u16* A = (z == 0) ? Aq : (z == 1) ? Ak : Av;
  const u16* W = (z == 0) ? Wq : (z == 1) ? Wk : Wv;
  u16* obf     = (z == 0) ? Oq : (z == 1) ? Ok : Ov;
  const float oscale = (z == 0) ? QSCALE : 1.0f;

  const int t = threadIdx.x;
  const int lane = t & 63;
  const int w = t >> 6;
  const int wr = w >> 1, wc = w & 1;
  const int m0 = blockIdx.x * 128;
  const int n0 = blockIdx.y * 128;
  f32x4 acc[4][4] = {};

  const int srow = t >> 3;              // + p*32
  const int scb = (t & 7) ^ (srow & 7); // swizzled colblock
  const int fr = lane & 15;
  const int fg = lane >> 4;
  const int fs7 = fr & 7;

  for (int k0 = 0; k0 < 1024; k0 += 64) {
#pragma unroll
    for (int p = 0; p < 4; ++p) {
      int r = p*32 + srow;
      gload16(A + (size_t)(m0 + r)*1024 + k0 + scb*8, &As[(p*256 + t)*8]);
      gload16(W + (size_t)(n0 + r)*1024 + k0 + scb*8, &Bs[(p*256 + t)*8]);
    }
    __syncthreads();
#pragma unroll
    for (int ks = 0; ks < 2; ++ks) {
      bf16x8 af[4], bfr[4];
#pragma unroll
      for (int i = 0; i < 4; ++i) {
        int ra = wr*64 + i*16 + fr;
        af[i]  = *(const bf16x8*)&As[ra*64 + (((ks*4 + fg) ^ fs7) * 8)];
        int rb = wc*64 + i*16 + fr;
        bfr[i] = *(const bf16x8*)&Bs[rb*64 + (((ks*4 + fg) ^ fs7) * 8)];
      }
#pragma unroll
      for (int i = 0; i < 4; ++i)
#pragma unroll
        for (int j = 0; j < 4; ++j)
          acc[i][j] = __builtin_amdgcn_mfma_f32_16x16x32_bf16(af[i], bfr[j], acc[i][j], 0, 0, 0);
    }
    __syncthreads();
  }

#pragma unroll
  for (int i = 0; i < 4; ++i) {
#pragma unroll
    for (int j = 0; j < 4; ++j) {
#pragma unroll
      for (int jj = 0; jj < 4; ++jj) {
        int row = m0 + wr*64 + i*16 + fg*4 + jj;   // verified C/D layout
        int col = n0 + wc*64 + j*16 + fr;
        float val = acc[i][j][jj];
        int b = row >> 11, n = row & 2047, h = col >> 6, dh = col & 63;
        if (z != 2) {
          obf[(((size_t)(b*H_ + h))*N_ + n)*DH_ + dh] = cvt_bf(val * oscale);
        } else {
          obf[(((size_t)(b*H_ + h))*DH_ + dh)*N_ + n] = cvt_bf(val);
        }
      }
    }
  }
}

// ---------------- output projection GEMM + residual, BK=64 ---------------
__global__ __launch_bounds__(256) void gemm_out(
    const u16* __restrict__ A, const u16* __restrict__ W,
    const float* __restrict__ resid, float* __restrict__ ofp)
{
  __shared__ __align__(16) u16 As[128*64];
  __shared__ __align__(16) u16 Bs[128*64];
  const int t = threadIdx.x;
  const int lane = t & 63;
  const int w = t >> 6;
  const int wr = w >> 1, wc = w & 1;
  const int m0 = blockIdx.x * 128;
  const int n0 = blockIdx.y * 128;
  f32x4 acc[4][4] = {};

  const int srow = t >> 3;
  const int scb = (t & 7) ^ (srow & 7);
  const int fr = lane & 15;
  const int fg = lane >> 4;
  const int fs7 = fr & 7;

  for (int k0 = 0; k0 < 1024; k0 += 64) {
#pragma unroll
    for (int p = 0; p < 4; ++p) {
      int r = p*32 + srow;
      gload16(A + (size_t)(m0 + r)*1024 + k0 + scb*8, &As[(p*256 + t)*8]);
      gload16(W + (size_t)(n0 + r)*1024 + k0 + scb*8, &Bs[(p*256 + t)*8]);
    }
    __syncthreads();
#pragma unroll
    for (int ks = 0; ks < 2; ++ks) {
      bf16x8 af[4], bfr[4];
#pragma unroll
      for (int i = 0; i < 4; ++i) {
        int ra = wr*64 + i*16 + fr;
        af[i]  = *(const bf16x8*)&As[ra*64 + (((ks*4 + fg) ^ fs7) * 8)];
        int rb = wc*64 + i*16 + fr;
        bfr[i] = *(const bf16x8*)&Bs[rb*64 + (((ks*4 + fg) ^ fs7) * 8)];
      }
#pragma unroll
      for (int i = 0; i < 4; ++i)
#pragma unroll
        for (int j = 0; j < 4; ++j)
          acc[i][j] = __builtin_amdgcn_mfma_f32_16x16x32_bf16(af[i], bfr[j], acc[i][j], 0, 0, 0);
    }
    __syncthreads();
  }

#pragma unroll
  for (int i = 0; i < 4; ++i)
#pragma unroll
    for (int j = 0; j < 4; ++j)
#pragma unroll
      for (int jj = 0; jj < 4; ++jj) {
        int row = m0 + wr*64 + i*16 + fg*4 + jj;
        int col = n0 + wc*64 + j*16 + fr;
        size_t idx = (size_t)row*1024 + col;
        ofp[idx] = acc[i][j][jj] + resid[idx];
      }
}

// ---------------- flash attention, swapped-operand 32x32, KVBLK=128 ------
// grid (B*H=64, N/256=8): all q-blocks of one bh land on one XCD (flat%8).
// block 512 = 8 waves; wave w owns q-rows q0+w*32..+32; P lane-local.
// Softmax VALU packed: v_max3 tree, v_pk_add sub/sum, v_pk_mul rescale.
__device__ __forceinline__ f32x2 sp2(const f32x16& S, int i) {
  f32x2 r; r.x = S[2*i]; r.y = S[2*i + 1]; return r;
}
// P^T B-frag assembly (T12): pf[0] = k 0..15, pf[1] = k 16..31 of S's chunk
__device__ __forceinline__ void buildP(const f32x16& S, bf16x8* pf) {
  unsigned w0 = cvt_pk(S[0], S[1]),  w1 = cvt_pk(S[2], S[3]);
  unsigned w2 = cvt_pk(S[4], S[5]),  w3 = cvt_pk(S[6], S[7]);
  i32x2 A2 = pl32swap(w0, w2), B2 = pl32swap(w1, w3);
  u32x4 f0 = { (unsigned)A2.x, (unsigned)B2.x, (unsigned)A2.y, (unsigned)B2.y };
  pf[0] = __builtin_bit_cast(bf16x8, f0);
  unsigned w4 = cvt_pk(S[8], S[9]),   w5 = cvt_pk(S[10], S[11]);
  unsigned w6 = cvt_pk(S[12], S[13]), w7 = cvt_pk(S[14], S[15]);
  i32x2 C2 = pl32swap(w4, w6), D2 = pl32swap(w5, w7);
  u32x4 f1 = { (unsigned)C2.x, (unsigned)D2.x, (unsigned)C2.y, (unsigned)D2.y };
  pf[1] = __builtin_bit_cast(bf16x8, f1);
}

__global__ __launch_bounds__(512, 2) void flash_attn(
    const u16* __restrict__ Qs, const u16* __restrict__ Ks,
    const u16* __restrict__ VTs, u16* __restrict__ ctx)
{
  __shared__ __align__(16) u16 Klds[2][128*64];   // [k 0..127][d 0..63]
  __shared__ __align__(16) u16 Vlds[2][64*128];   // [d 0..63][k 0..127]
  const int t = threadIdx.x;
  const int lane = t & 63;
  const int w = t >> 6;         // 0..7
  const int l31 = lane & 31;
  const int h = lane >> 5;      // half-wave
  const int bh = blockIdx.x;
  const int q0 = blockIdx.y * 256 + w * 32;
  const u16* Qbh = Qs  + (size_t)bh * N_ * DH_;
  const u16* Kbh = Ks  + (size_t)bh * N_ * DH_;
  const u16* Vbh = VTs + (size_t)bh * DH_ * N_;

  // Q B-frags: qf[dd] = Q[q0+l31][dd*16 + h*8 + 0..7]
  bf16x8 qf[4];
#pragma unroll
  for (int dd = 0; dd < 4; ++dd)
    qf[dd] = *(const bf16x8*)&Qbh[(size_t)(q0 + l31)*64 + dd*16 + h*8];

  float m = -1e30f;
  f32x2 lp2 = {0.f, 0.f};
  f32x16 O0 = {}, O1 = {};

  // staging (2 passes of 512 threads per matrix per tile)
  const int krow0 = t >> 3;                       // + p*64
  const int kcb   = (t & 7) ^ ((t >> 3) & 7);
  const int vrow0 = t >> 4;                       // + p*32
  const int vcb   = (t & 15) ^ ((t >> 4) & 7);
  const u16* ksrc = Kbh + (size_t)krow0*64 + kcb*8;   // + kv*64
  const u16* vsrc = Vbh + (size_t)vrow0*N_ + vcb*8;   // + kv

  auto stage = [&](int buf, int kv) {
#pragma unroll
    for (int p = 0; p < 2; ++p) {
      gload16(ksrc + (size_t)(kv + p*64)*64, &Klds[buf][(p*512 + t)*8]);
      gload16(vsrc + kv + (size_t)(p*32)*N_, &Vlds[buf][(p*512 + t)*8]);
    }
  };

  const int l7 = l31 & 7;

  stage(0, 0);
  __syncthreads();
  int cur = 0;

  for (int kv0 = 0; kv0 < N_; kv0 += 128) {
    if (kv0 + 128 < N_) stage(cur ^ 1, kv0 + 128);

#pragma unroll
    for (int half = 0; half < 2; ++half) {
      const int kb = half * 64;
      // S^T[k][q]: A = K rows, mfma-k = d
      f32x16 S0 = {}, S1 = {};
      __builtin_amdgcn_s_setprio(1);
#pragma unroll
      for (int dd = 0; dd < 4; ++dd) {
        int cb = ((2*dd + h) ^ l7) * 8;
        bf16x8 kf0 = *(const bf16x8*)&Klds[cur][(kb + l31)*64 + cb];
        bf16x8 kf1 = *(const bf16x8*)&Klds[cur][(kb + 32 + l31)*64 + cb];
        S0 = __builtin_amdgcn_mfma_f32_32x32x16_bf16(kf0, qf[dd], S0, 0, 0, 0);
        S1 = __builtin_amdgcn_mfma_f32_32x32x16_bf16(kf1, qf[dd], S1, 0, 0, 0);
      }
      __builtin_amdgcn_s_setprio(0);

      // ---- max via max3 tree (T17): 32 values in ~16 ops ----
      float t0 = m3(S0[0],  S0[1],  S0[2]);
      float t1 = m3(S0[3],  S0[4],  S0[5]);
      float t2 = m3(S0[6],  S0[7],  S0[8]);
      float t3 = m3(S0[9],  S0[10], S0[11]);
      float t4 = m3(S0[12], S0[13], S0[14]);
      float t5 = m3(S0[15], S1[0],  S1[1]);
      float t6 = m3(S1[2],  S1[3],  S1[4]);
      float t7 = m3(S1[5],  S1[6],  S1[7]);
      float t8 = m3(S1[8],  S1[9],  S1[10]);
      float t9 = m3(S1[11], S1[12], S1[13]);
      float ta = fmaxf(S1[14], S1[15]);
      float u0 = m3(t0, t1, t2);
      float u1 = m3(t3, t4, t5);
      float u2 = m3(t6, t7, t8);
      float u3 = fmaxf(t9, ta);
      float pm = m3(m3(u0, u1, u2), u3, -1e30f);
      i32x2 msw = pl32swap(__float_as_uint(pm), __float_as_uint(pm));
      pm = fmaxf(__uint_as_float((unsigned)msw.x), __uint_as_float((unsigned)msw.y));

      if (!__all(pm <= m + 8.f)) {          // T13 defer-max
        float mn = fmaxf(m, pm);
        float al = __builtin_amdgcn_exp2f(m - mn);
        m = mn;
        f32x2 al2; al2.x = al; al2.y = al;
        lp2 = pk_mul(lp2, al2);
#pragma unroll
        for (int r = 0; r < 8; ++r) {
          f32x2 p0 = pk_mul(sp2(O0, r), al2);
          O0[2*r] = p0.x; O0[2*r+1] = p0.y;
          f32x2 p1 = pk_mul(sp2(O1, r), al2);
          O1[2*r] = p1.x; O1[2*r+1] = p1.y;
        }
      }

      // ---- sub (packed) + exp2 ----
      f32x2 nm2; nm2.x = -m; nm2.y = -m;
#pragma unroll
      for (int r = 0; r < 8; ++r) {
        f32x2 p0 = pk_add(sp2(S0, r), nm2);
        S0[2*r]   = __builtin_amdgcn_exp2f(p0.x);
        S0[2*r+1] = __builtin_amdgcn_exp2f(p0.y);
        f32x2 p1 = pk_add(sp2(S1, r), nm2);
        S1[2*r]   = __builtin_amdgcn_exp2f(p1.x);
        S1[2*r+1] = __builtin_amdgcn_exp2f(p1.y);
      }

      // ---- sum tree (packed): 16 pairs -> 1 pair, accumulate into lp2 ----
      {
        f32x2 a0 = pk_add(sp2(S0,0), sp2(S0,1));
        f32x2 a1 = pk_add(sp2(S0,2), sp2(S0,3));
        f32x2 a2 = pk_add(sp2(S0,4), sp2(S0,5));
        f32x2 a3 = pk_add(sp2(S0,6), sp2(S0,7));
        f32x2 b0 = pk_add(sp2(S1,0), sp2(S1,1));
        f32x2 b1 = pk_add(sp2(S1,2), sp2(S1,3));
        f32x2 b2 = pk_add(sp2(S1,4), sp2(S1,5));
        f32x2 b3 = pk_add(sp2(S1,6), sp2(S1,7));
        a0 = pk_add(a0, a1); a2 = pk_add(a2, a3);
        b0 = pk_add(b0, b1); b2 = pk_add(b2, b3);
        a0 = pk_add(a0, a2); b0 = pk_add(b0, b2);
        lp2 = pk_add(lp2, pk_add(a0, b0));
      }

      bf16x8 pf[4];
      buildP(S0, &pf[0]);
      buildP(S1, &pf[2]);

      // O^T[d][q] += V^T[d][k-chunk] P^T
      __builtin_amdgcn_s_setprio(1);
#pragma unroll
      for (int ks = 0; ks < 4; ++ks) {
        int cb = ((half*8 + ks*2 + h) ^ l7) * 8;
        bf16x8 vf0 = *(const bf16x8*)&Vlds[cur][l31*128 + cb];
        bf16x8 vf1 = *(const bf16x8*)&Vlds[cur][(32 + l31)*128 + cb];
        O0 = __builtin_amdgcn_mfma_f32_32x32x16_bf16(vf0, pf[ks], O0, 0, 0, 0);
        O1 = __builtin_amdgcn_mfma_f32_32x32x16_bf16(vf1, pf[ks], O1, 0, 0, 0);
      }
      __builtin_amdgcn_s_setprio(0);
    }

    __syncthreads();   // all waves done with [cur]; prefetch landed
    cur ^= 1;
  }

  // combine pair + half-wave l, invert
  float lps = lp2.x + lp2.y;
  i32x2 lsw = pl32swap(__float_as_uint(lps), __float_as_uint(lps));
  float ltot = __uint_as_float((unsigned)lsw.x) + __uint_as_float((unsigned)lsw.y);
  float linv = __builtin_amdgcn_rcpf(ltot);
  f32x2 li2; li2.x = linv; li2.y = linv;

  // write ctx [B,N,D] bf16; lane q = q0+l31 holds d = (r&3)+8*(r>>2)+4h (+32)
  int b = bh >> 4, hh = bh & 15;
  unsigned* crow = (unsigned*)(ctx + ((size_t)b*N_ + (q0 + l31))*D_ + hh*64);
#pragma unroll
  for (int rp = 0; rp < 8; ++rp) {
    int r = rp*2;
    int d0 = (r & 3) + 8*(r >> 2) + 4*h;
    f32x2 o0 = pk_mul(sp2(O0, rp), li2);
    f32x2 o1 = pk_mul(sp2(O1, rp), li2);
    crow[d0 >> 1]        = cvt_pk(o0.x, o0.y);
    crow[(d0 + 32) >> 1] = cvt_pk(o1.x, o1.y);
  }
}

// ---------------- LayerNorm in-place on d_out ----------------
__global__ __launch_bounds__(256) void ln_fwd(float* __restrict__ io,
    const float* __restrict__ gamma, const float* __restrict__ beta)
{
  __shared__ float red[4];
  const int t = threadIdx.x;
  const int lane = t & 63, w = t >> 6;
  float4* row = (float4*)(io + (size_t)blockIdx.x * 1024);
  float4 x = row[t];
  float s = x.x + x.y + x.z + x.w;
#pragma unroll
  for (int m = 1; m < 64; m <<= 1) s += __shfl_xor(s, m);
  if (lane == 0) red[w] = s;
  __syncthreads();
  float mean = (red[0] + red[1] + red[2] + red[3]) * (1.f/1024.f);
  __syncthreads();
  float dx0 = x.x - mean, dx1 = x.y - mean, dx2 = x.z - mean, dx3 = x.w - mean;
  float sq = dx0*dx0 + dx1*dx1 + dx2*dx2 + dx3*dx3;
#pragma unroll
  for (int m = 1; m < 64; m <<= 1) sq += __shfl_xor(sq, m);
  if (lane == 0) red[w] = sq;
  __syncthreads();
  float var = (red[0] + red[1] + red[2] + red[3]) * (1.f/1024.f);
  float rstd = rsqrtf(var + 1e-5f);
  float4 g = ((const float4*)gamma)[t];
  float4 bb = ((const float4*)beta)[t];
  float4 y;
  y.x = dx0*rstd*g.x + bb.x;
  y.y = dx1*rstd*g.y + bb.y;
  y.z = dx2*rstd*g.z + bb.z;
  y.w = dx3*rstd*g.w + bb.w;
  row[t] = y;
}

extern "C" void kernel_launch(void* const* d_in, const int* in_sizes, int n_in,
                              void* d_out, int out_size, void* d_ws, size_t ws_size,
                              hipStream_t stream) {
  const float* q     = (const float*)d_in[0];
  const float* k     = (const float*)d_in[1];
  const float* v     = (const float*)d_in[2];
  const float* Wq    = (const float*)d_in[3];
  const float* Wk    = (const float*)d_in[4];
  const float* Wv    = (const float*)d_in[5];
  const float* Wo    = (const float*)d_in[6];
  const float* gamma = (const float*)d_in[7];
  const float* beta  = (const float*)d_in[8];
  float* out = (float*)d_out;

  char* ws = (char*)d_ws;
  const size_t MB = 1024*1024;
  u16* qb  = (u16*)(ws + 0*MB);    // 16 MB each
  u16* kb  = (u16*)(ws + 16*MB);
  u16* vb  = (u16*)(ws + 32*MB);
  u16* Wqb = (u16*)(ws + 48*MB);   // 2 MB each
  u16* Wkb = (u16*)(ws + 50*MB);
  u16* Wvb = (u16*)(ws + 52*MB);
  u16* Wob = (u16*)(ws + 54*MB);
  u16* Qs  = (u16*)(ws + 56*MB);   // [B,H,N,Dh] bf16 (pre-scaled by QSCALE)
  u16* Ks  = (u16*)(ws + 72*MB);   // [B,H,N,Dh]
  u16* VTs = (u16*)(ws + 88*MB);   // [B,H,Dh,N]
  u16* ctx = (u16*)(ws + 0*MB);    // reuse qb region after Q-proj

  const int ntot4 = 3*((B_*N_*D_)/4) + 4*((D_*D_)/4);   // 7M
  cast_all<<<ntot4/256, 256, 0, stream>>>(q, k, v, Wq, Wk, Wv, Wo,
                                          qb, kb, vb, Wqb, Wkb, Wvb, Wob);

  dim3 gproj(M_/128, D_/128, 3);   // (64, 8, 3)
  gemm_qkv<<<gproj, 256, 0, stream>>>(qb, kb, vb, Wqb, Wkb, Wvb, Qs, Ks, VTs);

  flash_attn<<<dim3(B_*H_, N_/256), 512, 0, stream>>>(Qs, Ks, VTs, ctx);

  gemm_out<<<dim3(M_/128, D_/128), 256, 0, stream>>>(ctx, Wob, q, out);

  ln_fwd<<<M_, 256, 0, stream>>>(out, gamma, beta);
}